// Round 2
// baseline (3173.077 us; speedup 1.0000x reference)
//
#include <hip/hip_runtime.h>
#include <hip/hip_bf16.h>

// Swin window MHSA, MI355X. fp32 I/O (per reference dtypes), fused
// per-(batch,window) kernel, fp32 vector compute, bf16 LDS tiles.
// Algebra: S = X^T G X + rank-1 bias terms, Y = sum_h Wov_h (X wmap_h) + cvec,
// with G_h = Wk_h^T Wq_h, Wov_h = Wo_h Wv_h precomputed per call into d_ws.

#define NBATCH 8
#define NHEAD  8

__device__ __forceinline__ float b2f(unsigned short u) {
  union { unsigned int i; float f; } v; v.i = ((unsigned int)u) << 16; return v.f;
}
__device__ __forceinline__ unsigned short f2b(float f) {
  union { float f; unsigned int u; } v; v.f = f;
  unsigned int u = v.u;
  return (unsigned short)((u + 0x7FFFu + ((u >> 16) & 1u)) >> 16);
}
__device__ __forceinline__ int regof(int y) { return (y < 49) ? 0 : ((y < 53) ? 1 : 2); }

// ---- Gt[h][b][a] = sum_dd Wk[h*256+dd][a] * Wq[h*256+dd][b] ----
__global__ void k_gt(const float* __restrict__ Wk,
                     const float* __restrict__ Wq,
                     float* __restrict__ Gt) {
  int h = blockIdx.x >> 6;
  int b0 = (blockIdx.x & 63) << 2;
  int a = threadIdx.x;
  const float* wkh = Wk + h * 65536;
  const float* wqh = Wq + h * 65536;
  float a0 = 0.f, a1 = 0.f, a2 = 0.f, a3 = 0.f;
  for (int dd = 0; dd < 256; ++dd) {
    float wk = wkh[dd * 256 + a];
    float4 w4 = *(const float4*)(wqh + dd * 256 + b0);
    a0 += wk * w4.x;
    a1 += wk * w4.y;
    a2 += wk * w4.z;
    a3 += wk * w4.w;
  }
  float* gout = Gt + (h * 256 + b0) * 256 + a;
  gout[0] = a0; gout[256] = a1; gout[512] = a2; gout[768] = a3;
}

// ---- Wovt[h][d][o] = sum_dd Wo[o][h*256+dd] * Wv[h*256+dd][d] ----
__global__ void k_wov(const float* __restrict__ Wo,
                      const float* __restrict__ Wv,
                      float* __restrict__ Wovt) {
  int h = blockIdx.x >> 6;
  int d0 = (blockIdx.x & 63) << 2;
  int o = threadIdx.x;
  float a0 = 0.f, a1 = 0.f, a2 = 0.f, a3 = 0.f;
  const float* wob = Wo + o * 2048 + h * 256;
  for (int dd = 0; dd < 256; ++dd) {
    float wo = wob[dd];
    float4 w4 = *(const float4*)(Wv + (h * 256 + dd) * 256 + d0);
    a0 += wo * w4.x;
    a1 += wo * w4.y;
    a2 += wo * w4.z;
    a3 += wo * w4.w;
  }
  float* wout = Wovt + (h * 256 + d0) * 256 + o;
  wout[0] = a0; wout[256] = a1; wout[512] = a2; wout[768] = a3;
}

// ---- bias vectors: w1_h[b]=bk_h.Wq_h[:,b], w2_h[a]=bq_h.Wk_h[:,a],
//      c0_h=bk_h.bq_h, cvec[o]=bo[o]+sum_hd Wo[o][hd]*bv[hd] ----
__global__ void k_vecs(const float* __restrict__ Wk,
                       const float* __restrict__ Wq,
                       const float* __restrict__ bk,
                       const float* __restrict__ bq,
                       const float* __restrict__ Wo,
                       const float* __restrict__ bv,
                       const float* __restrict__ bo,
                       float* __restrict__ w1, float* __restrict__ w2,
                       float* __restrict__ c0, float* __restrict__ cvec) {
  int blk = blockIdx.x;
  int t = threadIdx.x;
  if (blk < 8) {
    int h = blk;
    float s1 = 0.f, s2 = 0.f;
    for (int dd = 0; dd < 256; ++dd) {
      float bkv = bk[h * 256 + dd];
      float bqv = bq[h * 256 + dd];
      s1 += bkv * Wq[(h * 256 + dd) * 256 + t];
      s2 += bqv * Wk[(h * 256 + dd) * 256 + t];
    }
    w1[h * 256 + t] = s1;
    w2[h * 256 + t] = s2;
    if (t == 0) {
      float c = 0.f;
      for (int dd = 0; dd < 256; ++dd)
        c += bk[h * 256 + dd] * bq[h * 256 + dd];
      c0[h] = c;
    }
  } else {
    int o = t;
    float acc = bo[o];
    const float* wob = Wo + o * 2048;
    for (int hd = 0; hd < 2048; ++hd)
      acc += wob[hd] * bv[hd];
    cvec[o] = acc;
  }
}

// ---- main fused kernel: one block per (n, window) ----
__global__ __launch_bounds__(256, 2) void k_attn(
    const float* __restrict__ X,     // [8][256][3136] fp32
    const float* __restrict__ relc,  // [169][8] fp32
    const float* __restrict__ Gt,
    const float* __restrict__ Wovt,
    const float* __restrict__ w1,
    const float* __restrict__ w2,
    const float* __restrict__ c0v,
    const float* __restrict__ cvec,
    float* __restrict__ out) {

  __shared__ unsigned short Xs[256 * 54];  // X window, bf16, row stride 54
  __shared__ unsigned short Ms[256 * 54];  // M = G X, then T = X wmap (bf16)
  __shared__ float Ss[49 * 49];            // scores / wmap
  __shared__ float aqs[49];
  __shared__ float bps[49];

  const int tid = threadIdx.x;
  const int n = blockIdx.x >> 6;
  const int g = blockIdx.x & 63;
  const int gi = g >> 3, gj = g & 7;

  // ---- load rolled window into LDS ----
  {
    const int d = tid;
    const int c = d >> 4, p1 = (d >> 2) & 3, p2 = d & 3;
    const float* xin = X + n * (256 * 3136);
    for (int t = 0; t < 49; ++t) {
      int wi = t / 7, wj = t - wi * 7;
      int y = (gi * 7 + wi) * 4 + p1;
      int x = (gj * 7 + wj) * 4 + p2;
      int ys = y - 3; if (ys < 0) ys += 224;
      int xs = x - 3; if (xs < 0) xs += 224;
      int ds = c * 16 + (ys & 3) * 4 + (xs & 3);
      int ts = (ys >> 2) * 56 + (xs >> 2);
      Xs[d * 54 + t] = f2b(xin[ds * 3136 + ts]);
    }
#pragma unroll
    for (int t = 49; t < 54; ++t) { Xs[d * 54 + t] = 0; Ms[d * 54 + t] = 0; }
  }

  const int a0 = (tid >> 2) << 2;     // row chunk (4 rows)
  const int qc = tid & 3;
  const int q0 = qc * 13;             // token chunk (13, last chunk uses 10)
  const int p3p = tid & 63;           // phase-3 key index
  const int p3q0 = (tid >> 6) * 13;   // phase-3 query chunk

  float yacc[4][13];
#pragma unroll
  for (int i = 0; i < 4; ++i)
#pragma unroll
    for (int j = 0; j < 13; ++j) yacc[i][j] = 0.f;

  for (int h = 0; h < NHEAD; ++h) {
    __syncthreads();  // Xs visible (h=0); Ms/Ss free for reuse (h>0)

    // ---- phase 2: M = G_h @ Xwin  [256 x 49] -> Ms (bf16) ----
    {
      float acc[4][13];
#pragma unroll
      for (int i = 0; i < 4; ++i)
#pragma unroll
        for (int j = 0; j < 13; ++j) acc[i][j] = 0.f;
      const float* gb = Gt + (h * 256) * 256 + a0;
#pragma unroll 2
      for (int b = 0; b < 256; ++b) {
        const float4 g4 = *(const float4*)(gb + b * 256);
        float xv[13];
#pragma unroll
        for (int j = 0; j < 13; ++j) xv[j] = b2f(Xs[b * 54 + q0 + j]);
#pragma unroll
        for (int j = 0; j < 13; ++j) {
          acc[0][j] += g4.x * xv[j];
          acc[1][j] += g4.y * xv[j];
          acc[2][j] += g4.z * xv[j];
          acc[3][j] += g4.w * xv[j];
        }
      }
#pragma unroll
      for (int i = 0; i < 4; ++i)
#pragma unroll
        for (int j = 0; j < 13; ++j)
          if (q0 + j < 49) Ms[(a0 + i) * 54 + q0 + j] = f2b(acc[i][j]);
    }

    // ---- rank-1 bias terms a_q, b_p ----
    if (tid < 49) {
      const float* w1h = w1 + h * 256;
      float acc = 0.f;
      for (int dd = 0; dd < 256; ++dd) acc += w1h[dd] * b2f(Xs[dd * 54 + tid]);
      aqs[tid] = acc;
    } else if (tid >= 64 && tid < 113) {
      int t = tid - 64;
      const float* w2h = w2 + h * 256;
      float acc = 0.f;
      for (int dd = 0; dd < 256; ++dd) acc += w2h[dd] * b2f(Xs[dd * 54 + t]);
      bps[t] = acc;
    }
    __syncthreads();

    // ---- phase 3: S[p,q] = (X^T M + aq + bp + c0)/16 + rel + mask ----
    if (p3p < 49) {
      const int p = p3p;
      float acc[13];
#pragma unroll
      for (int j = 0; j < 13; ++j) acc[j] = 0.f;
      for (int a = 0; a < 256; ++a) {
        float xv = b2f(Xs[a * 54 + p]);
#pragma unroll
        for (int j = 0; j < 13; ++j) acc[j] += xv * b2f(Ms[a * 54 + p3q0 + j]);
      }
      const float c0h = c0v[h];
      const float bpv = bps[p];
      const int yp = p / 7, xp = p - yp * 7;
      const int fp = regof(gi * 7 + yp) * 3 + regof(gj * 7 + xp);
#pragma unroll
      for (int j = 0; j < 13; ++j) {
        int q = p3q0 + j;
        if (q < 49) {
          int yq = q / 7, xq = q - yq * 7;
          int fq = regof(gi * 7 + yq) * 3 + regof(gj * 7 + xq);
          float rel = relc[((yp - yq + 6) + 13 * (xp - xq + 6)) * 8 + h];
          float v = (acc[j] + aqs[q] + bpv + c0h) * 0.0625f + rel;
          if (fp != fq) v -= 100.f;
          Ss[p * 49 + q] = v;
        }
      }
    }
    __syncthreads();

    // ---- softmax over keys p for each query column q ----
    if (tid < 49) {
      const int q = tid;
      float m = -1e30f;
      for (int p = 0; p < 49; ++p) m = fmaxf(m, Ss[p * 49 + q]);
      float s = 0.f;
      for (int p = 0; p < 49; ++p) {
        float e = __expf(Ss[p * 49 + q] - m);
        Ss[p * 49 + q] = e;
        s += e;
      }
      float inv = 1.f / s;
      for (int p = 0; p < 49; ++p) Ss[p * 49 + q] *= inv;
    }
    __syncthreads();

    // ---- phase T: T = Xwin @ wmap  [256 x 49] -> Ms (bf16) ----
    {
      float acc[4][13];
#pragma unroll
      for (int i = 0; i < 4; ++i)
#pragma unroll
        for (int j = 0; j < 13; ++j) acc[i][j] = 0.f;
      for (int p = 0; p < 49; ++p) {
        float x0 = b2f(Xs[(a0 + 0) * 54 + p]);
        float x1 = b2f(Xs[(a0 + 1) * 54 + p]);
        float x2 = b2f(Xs[(a0 + 2) * 54 + p]);
        float x3 = b2f(Xs[(a0 + 3) * 54 + p]);
#pragma unroll
        for (int j = 0; j < 13; ++j) {
          int q = q0 + j;
          float wv = Ss[p * 49 + (q < 49 ? q : 48)];  // clamp: dead lanes only
          acc[0][j] += x0 * wv;
          acc[1][j] += x1 * wv;
          acc[2][j] += x2 * wv;
          acc[3][j] += x3 * wv;
        }
      }
#pragma unroll
      for (int i = 0; i < 4; ++i)
#pragma unroll
        for (int j = 0; j < 13; ++j)
          if (q0 + j < 49) Ms[(a0 + i) * 54 + q0 + j] = f2b(acc[i][j]);
    }
    __syncthreads();

    // ---- phase 4: yacc += Wov_h @ T ----
    {
      const float* wb = Wovt + (h * 256) * 256 + a0;
#pragma unroll 2
      for (int d = 0; d < 256; ++d) {
        const float4 w4 = *(const float4*)(wb + d * 256);
#pragma unroll
        for (int j = 0; j < 13; ++j) {
          float tv = b2f(Ms[d * 54 + q0 + j]);
          yacc[0][j] += w4.x * tv;
          yacc[1][j] += w4.y * tv;
          yacc[2][j] += w4.z * tv;
          yacc[3][j] += w4.w * tv;
        }
      }
    }
  }

  // ---- epilogue: + cvec, write fp32 output (still in shifted coords) ----
  float* obase = out + n * (256 * 3136);
#pragma unroll
  for (int i = 0; i < 4; ++i) {
    float cv = cvec[a0 + i];
#pragma unroll
    for (int j = 0; j < 13; ++j) {
      int t = q0 + j;
      if (t < 49) {
        int wi = t / 7, wj = t - wi * 7;
        int pos = (gi * 7 + wi) * 56 + (gj * 7 + wj);
        obase[(a0 + i) * 3136 + pos] = yacc[i][j] + cv;
      }
    }
  }
}

extern "C" void kernel_launch(void* const* d_in, const int* in_sizes, int n_in,
                              void* d_out, int out_size, void* d_ws, size_t ws_size,
                              hipStream_t stream) {
  (void)in_sizes; (void)n_in; (void)out_size; (void)ws_size;
  const float* X  = (const float*)d_in[0];
  const float* Wk = (const float*)d_in[1];
  const float* bk = (const float*)d_in[2];
  const float* Wq = (const float*)d_in[3];
  const float* bq = (const float*)d_in[4];
  const float* Wv = (const float*)d_in[5];
  const float* bv = (const float*)d_in[6];
  const float* Wo = (const float*)d_in[7];
  const float* bo = (const float*)d_in[8];
  const float* rc = (const float*)d_in[9];

  float* ws = (float*)d_ws;
  float* Gt   = ws;                       // 8*256*256 = 524288 f
  float* Wov  = ws + 524288;              // 8*256*256 = 524288 f
  float* w1   = ws + 1048576;             // 2048 f
  float* w2   = ws + 1050624;             // 2048 f
  float* c0   = ws + 1052672;             // 8 f
  float* cv   = ws + 1052680;             // 256 f
  float* out  = (float*)d_out;

  k_gt  <<<dim3(512), dim3(256), 0, stream>>>(Wk, Wq, Gt);
  k_wov <<<dim3(512), dim3(256), 0, stream>>>(Wo, Wv, Wov);
  k_vecs<<<dim3(9),   dim3(256), 0, stream>>>(Wk, Wq, bk, bq, Wo, bv, bo, w1, w2, c0, cv);
  k_attn<<<dim3(NBATCH * 64), dim3(256), 0, stream>>>(X, rc, Gt, Wov, w1, w2, c0, cv, out);
}

// Round 3
// 449.178 us; speedup vs baseline: 7.0642x; 7.0642x over previous
//
#include <hip/hip_runtime.h>
#include <hip/hip_bf16.h>

// Swin window MHSA, MI355X, MFMA version.
// Algebra: S = X^T G X + rank-1 bias, Y = sum_h Wov_h (X wmap_h) + cvec,
// G_h = Wk_h^T Wq_h, Wov_h = Wo_h Wv_h precomputed as bf16 in d_ws.
// One block per (batch, window); 512 threads = 8 waves; all 4 matmul phases
// on v_mfma_f32_16x16x32_bf16 with LDS layouts giving contiguous 16B frags.

#define NBATCH 8
#define NHEAD  8

typedef unsigned short ushort_t;
typedef __attribute__((ext_vector_type(8))) short bf16x8;   // 8 bf16 = 4 VGPR
typedef __attribute__((ext_vector_type(4))) float f32x4;    // MFMA acc

__device__ __forceinline__ float b2f(ushort_t u) {
  union { unsigned int i; float f; } v; v.i = ((unsigned int)u) << 16; return v.f;
}
__device__ __forceinline__ ushort_t f2b(float f) {
  union { float f; unsigned int u; } v; v.f = f;
  unsigned int u = v.u;
  return (ushort_t)((u + 0x7FFFu + ((u >> 16) & 1u)) >> 16);
}
__device__ __forceinline__ int regof(int y) { return (y < 49) ? 0 : ((y < 53) ? 1 : 2); }
__device__ __forceinline__ int div7(int t) { return (t * 37) >> 8; }  // t/7 for t<64

// ---- prep: Gbf[h][a][b] = sum_dd Wk[h,dd,a]*Wq[h,dd,b]  (blocks 0..511)
//            Wovbf[h][o][d] = sum_dd Wo[o][h,dd]*Wv[h,dd,d] (blocks 512..1023)
__global__ void k_gw(const float* __restrict__ Wk, const float* __restrict__ Wq,
                     const float* __restrict__ Wo, const float* __restrict__ Wv,
                     ushort_t* __restrict__ Gbf, ushort_t* __restrict__ Wovbf) {
  int blk = blockIdx.x;
  int t = threadIdx.x;
  if (blk < 512) {
    int h = blk >> 6, b0 = (blk & 63) << 2, a = t;
    const float* wkh = Wk + h * 65536;
    const float* wqh = Wq + h * 65536;
    float a0 = 0.f, a1 = 0.f, a2 = 0.f, a3 = 0.f;
    for (int dd = 0; dd < 256; ++dd) {
      float wk = wkh[dd * 256 + a];
      float4 w4 = *(const float4*)(wqh + dd * 256 + b0);
      a0 += wk * w4.x; a1 += wk * w4.y; a2 += wk * w4.z; a3 += wk * w4.w;
    }
    ushort4 u; u.x = f2b(a0); u.y = f2b(a1); u.z = f2b(a2); u.w = f2b(a3);
    *(ushort4*)(Gbf + h * 65536 + a * 256 + b0) = u;
  } else {
    int bb = blk - 512;
    int h = bb >> 6, d0 = (bb & 63) << 2, o = t;
    const float* wob = Wo + o * 2048 + h * 256;
    float a0 = 0.f, a1 = 0.f, a2 = 0.f, a3 = 0.f;
    for (int dd = 0; dd < 256; ++dd) {
      float wo = wob[dd];
      float4 w4 = *(const float4*)(Wv + (h * 256 + dd) * 256 + d0);
      a0 += wo * w4.x; a1 += wo * w4.y; a2 += wo * w4.z; a3 += wo * w4.w;
    }
    ushort4 u; u.x = f2b(a0); u.y = f2b(a1); u.z = f2b(a2); u.w = f2b(a3);
    *(ushort4*)(Wovbf + h * 65536 + o * 256 + d0) = u;
  }
}

// ---- bias vectors (fp32): w1_h[b]=bk_h.Wq_h[:,b], w2_h[a]=bq_h.Wk_h[:,a],
//      c0_h=bk_h.bq_h, cvec[o]=bo[o]+sum_hd Wo[o][hd]*bv[hd]
__global__ void k_vecs(const float* __restrict__ Wk, const float* __restrict__ Wq,
                       const float* __restrict__ bk, const float* __restrict__ bq,
                       const float* __restrict__ Wo, const float* __restrict__ bv,
                       const float* __restrict__ bo,
                       float* __restrict__ w1, float* __restrict__ w2,
                       float* __restrict__ c0, float* __restrict__ cvec) {
  int blk = blockIdx.x, t = threadIdx.x;
  if (blk < 8) {
    int h = blk;
    float s1 = 0.f, s2 = 0.f;
    for (int dd = 0; dd < 256; ++dd) {
      s1 += bk[h * 256 + dd] * Wq[(h * 256 + dd) * 256 + t];
      s2 += bq[h * 256 + dd] * Wk[(h * 256 + dd) * 256 + t];
    }
    w1[h * 256 + t] = s1;
    w2[h * 256 + t] = s2;
    if (t == 0) {
      float c = 0.f;
      for (int dd = 0; dd < 256; ++dd) c += bk[h * 256 + dd] * bq[h * 256 + dd];
      c0[h] = c;
    }
  } else {
    int o = t;
    float acc = bo[o];
    const float* wob = Wo + o * 2048;
    for (int hd = 0; hd < 2048; ++hd) acc += wob[hd] * bv[hd];
    cvec[o] = acc;
  }
}

// ---- main fused MFMA kernel: one block per (n, window), 512 threads ----
#define XS_STR 72    // Xs [256 d][72 p] bf16  (pad 49->72, 16B-aligned rows)
#define XT_STR 264   // Xt/MT [64][264] bf16
#define ST_STR 68    // St [64 q][68] f32; Wt (bf16) aliases row starts

__global__ __launch_bounds__(512, 2) void k_attn(
    const float* __restrict__ X,          // [8][256][3136] fp32
    const float* __restrict__ relc,       // [169][8] fp32
    const ushort_t* __restrict__ Gbf,     // [8][256 a][256 b] bf16
    const ushort_t* __restrict__ Wovbf,   // [8][256 o][256 d] bf16
    const float* __restrict__ w1, const float* __restrict__ w2,
    const float* __restrict__ c0v, const float* __restrict__ cvec,
    float* __restrict__ out) {

  __shared__ ushort_t Xs[256 * XS_STR];   // [d][p]
  __shared__ ushort_t Xt[64 * XT_STR];    // [p|q][d]
  __shared__ ushort_t MT[64 * XT_STR];    // Mt[q][a] then Tt[q][d]
  __shared__ float    St[64 * ST_STR];    // scores [q][p]; wmap^T bf16 in-place
  __shared__ float    aqs[64];
  __shared__ float    bps[64];
  __shared__ float    relL[169];

  const int tid  = threadIdx.x;
  const int wave = tid >> 6;
  const int lane = tid & 63;
  const int quad = lane >> 4;
  const int l16  = lane & 15;
  const int n  = blockIdx.x >> 6;
  const int g  = blockIdx.x & 63;
  const int gi = g >> 3, gj = g & 7;

  // ---- prologue: gather rolled window -> Xs[d][p] and Xt[p][d] ----
  {
    const int d = tid >> 1, half = tid & 1;
    const int c = d >> 4, p1 = (d >> 2) & 3, p2 = d & 3;
    const float* xin = X + n * (256 * 3136);
    const int pbeg = half * 25, pend = half ? 49 : 25;
    for (int p = pbeg; p < pend; ++p) {
      int wi = div7(p), wj = p - wi * 7;
      int y = (gi * 7 + wi) * 4 + p1;
      int x = (gj * 7 + wj) * 4 + p2;
      int ys = y - 3; if (ys < 0) ys += 224;
      int xs = x - 3; if (xs < 0) xs += 224;
      int ds = c * 16 + (ys & 3) * 4 + (xs & 3);
      int ts = (ys >> 2) * 56 + (xs >> 2);
      ushort_t v = f2b(xin[ds * 3136 + ts]);
      Xs[d * XS_STR + p] = v;
      Xt[p * XT_STR + d] = v;
    }
    // zero Xs pad cols p=49..71 (read by phase-T k-dim)
    for (int p = 49 + half * 12; p < 49 + half * 12 + (half ? 11 : 12); ++p)
      Xs[d * XS_STR + p] = 0;
  }
  // zero Xt pad rows p=49..63
  for (int i = tid; i < 15 * XT_STR; i += 512) Xt[49 * XT_STR + i] = 0;

  // Yt accumulators: o-tiles {2*wave, 2*wave+1} x q-tiles 0..3
  f32x4 yac[2][4];
#pragma unroll
  for (int i = 0; i < 2; ++i)
#pragma unroll
    for (int j = 0; j < 4; ++j) yac[i][j] = (f32x4){0.f, 0.f, 0.f, 0.f};

  const int at0 = wave * 2;  // a/d/o tile pair owned by this wave (phases 2,T,4)

  for (int h = 0; h < NHEAD; ++h) {
    __syncthreads();  // S0: prev phase4 done; MT/St free; Xs/Xt stable

    // ---- rel table + rank-1 bias terms ----
    if (tid < 169) relL[tid] = relc[tid * 8 + h];
    {
      const int q = tid >> 3, sub = tid & 7;
      const float* w1h = w1 + h * 256;
      const float* w2h = w2 + h * 256;
      float sa = 0.f, sb = 0.f;
      for (int i = 0; i < 32; ++i) {
        int dd = sub * 32 + i;
        float xv = b2f(Xt[q * XT_STR + dd]);
        sa += w1h[dd] * xv;
        sb += w2h[dd] * xv;
      }
      sa += __shfl_xor(sa, 1); sb += __shfl_xor(sb, 1);
      sa += __shfl_xor(sa, 2); sb += __shfl_xor(sb, 2);
      sa += __shfl_xor(sa, 4); sb += __shfl_xor(sb, 4);
      if (sub == 0) { aqs[q] = sa; bps[q] = sb; }
    }

    // ---- phase 2: Mt[q][a] = (G_h^T X)[a][q], MFMA ----
    {
      const ushort_t* gh = Gbf + h * 65536;
      f32x4 acc[2][4];
#pragma unroll
      for (int i = 0; i < 2; ++i)
#pragma unroll
        for (int j = 0; j < 4; ++j) acc[i][j] = (f32x4){0.f, 0.f, 0.f, 0.f};
#pragma unroll
      for (int k = 0; k < 8; ++k) {
        bf16x8 af[2], bf[4];
#pragma unroll
        for (int i = 0; i < 2; ++i)
          af[i] = *(const bf16x8*)(gh + ((at0 + i) * 16 + l16) * 256 + k * 32 + quad * 8);
#pragma unroll
        for (int j = 0; j < 4; ++j)
          bf[j] = *(const bf16x8*)(&Xt[(j * 16 + l16) * XT_STR + k * 32 + quad * 8]);
#pragma unroll
        for (int i = 0; i < 2; ++i)
#pragma unroll
          for (int j = 0; j < 4; ++j)
            acc[i][j] = __builtin_amdgcn_mfma_f32_16x16x32_bf16(af[i], bf[j], acc[i][j], 0, 0, 0);
      }
#pragma unroll
      for (int i = 0; i < 2; ++i)
#pragma unroll
        for (int j = 0; j < 4; ++j) {
          ushort4 u;
          u.x = f2b(acc[i][j][0]); u.y = f2b(acc[i][j][1]);
          u.z = f2b(acc[i][j][2]); u.w = f2b(acc[i][j][3]);
          *(ushort4*)(&MT[(j * 16 + l16) * XT_STR + (at0 + i) * 16 + quad * 4]) = u;
        }
    }
    __syncthreads();  // S1: Mt + biases ready

    // ---- phase 3: S[p][q] = X^T M + biases -> St[q][p] (masked, scaled) ----
    {
      const int ptile = wave & 3;
      const int qt0 = (wave >> 2) * 2;
      f32x4 acc[2];
#pragma unroll
      for (int j = 0; j < 2; ++j) acc[j] = (f32x4){0.f, 0.f, 0.f, 0.f};
#pragma unroll
      for (int k = 0; k < 8; ++k) {
        bf16x8 af = *(const bf16x8*)(&Xt[(ptile * 16 + l16) * XT_STR + k * 32 + quad * 8]);
#pragma unroll
        for (int j = 0; j < 2; ++j) {
          bf16x8 bf = *(const bf16x8*)(&MT[((qt0 + j) * 16 + l16) * XT_STR + k * 32 + quad * 8]);
          acc[j] = __builtin_amdgcn_mfma_f32_16x16x32_bf16(af, bf, acc[j], 0, 0, 0);
        }
      }
      const float c0h = c0v[h];
#pragma unroll
      for (int j = 0; j < 2; ++j) {
        const int q = (qt0 + j) * 16 + l16;
        const int yq = div7(q), xq = q - yq * 7;
        const int fq = regof(gi * 7 + yq) * 3 + regof(gj * 7 + xq);
        const float aqv = aqs[q];
        float4 sv;
        float* svp = &sv.x;
#pragma unroll
        for (int r = 0; r < 4; ++r) {
          int p = ptile * 16 + quad * 4 + r;
          float val = -1e30f;
          if (p < 49) {
            int yp = div7(p), xp = p - yp * 7;
            int fp = regof(gi * 7 + yp) * 3 + regof(gj * 7 + xp);
            float rel = relL[(yp - yq + 6) + 13 * (xp - xq + 6)];
            val = (acc[j][r] + aqv + bps[p] + c0h) * 0.0625f + rel;
            if (fp != fq) val -= 100.f;
          }
          svp[r] = val;
        }
        *(float4*)(&St[q * ST_STR + ptile * 16 + quad * 4]) = sv;
      }
    }
    __syncthreads();  // S2: St ready

    // ---- softmax over p per row q; write wmap^T bf16 in-place ----
    {
      const int q = tid >> 3, sub = tid & 7, p0 = sub * 8;
      float v[8];
#pragma unroll
      for (int i = 0; i < 8; ++i) v[i] = St[q * ST_STR + p0 + i];
      float m = v[0];
#pragma unroll
      for (int i = 1; i < 8; ++i) m = fmaxf(m, v[i]);
      m = fmaxf(m, __shfl_xor(m, 1));
      m = fmaxf(m, __shfl_xor(m, 2));
      m = fmaxf(m, __shfl_xor(m, 4));
      float s = 0.f;
#pragma unroll
      for (int i = 0; i < 8; ++i) { v[i] = __expf(v[i] - m); s += v[i]; }
      s += __shfl_xor(s, 1);
      s += __shfl_xor(s, 2);
      s += __shfl_xor(s, 4);
      float inv = 1.f / s;
      uint4 pk;
      unsigned int* pkp = &pk.x;
#pragma unroll
      for (int i = 0; i < 4; ++i) {
        unsigned int lo = f2b(v[2 * i] * inv);
        unsigned int hi = f2b(v[2 * i + 1] * inv);
        pkp[i] = lo | (hi << 16);
      }
      ushort_t* wrow = (ushort_t*)(&St[q * ST_STR]);
      *(uint4*)(&wrow[p0]) = pk;
    }
    __syncthreads();  // S3: wmap^T (Wt) ready

    // ---- phase T: Tt[q][d] = (X wmap)[d][q], MFMA ----
    {
      f32x4 acc[2][4];
#pragma unroll
      for (int i = 0; i < 2; ++i)
#pragma unroll
        for (int j = 0; j < 4; ++j) acc[i][j] = (f32x4){0.f, 0.f, 0.f, 0.f};
#pragma unroll
      for (int k = 0; k < 2; ++k) {
        bf16x8 af[2], bf[4];
#pragma unroll
        for (int i = 0; i < 2; ++i)
          af[i] = *(const bf16x8*)(&Xs[((at0 + i) * 16 + l16) * XS_STR + k * 32 + quad * 8]);
#pragma unroll
        for (int j = 0; j < 4; ++j) {
          const ushort_t* wrow = (const ushort_t*)(&St[(j * 16 + l16) * ST_STR]);
          bf[j] = *(const bf16x8*)(&wrow[k * 32 + quad * 8]);
        }
#pragma unroll
        for (int i = 0; i < 2; ++i)
#pragma unroll
          for (int j = 0; j < 4; ++j)
            acc[i][j] = __builtin_amdgcn_mfma_f32_16x16x32_bf16(af[i], bf[j], acc[i][j], 0, 0, 0);
      }
#pragma unroll
      for (int i = 0; i < 2; ++i)
#pragma unroll
        for (int j = 0; j < 4; ++j) {
          ushort4 u;
          u.x = f2b(acc[i][j][0]); u.y = f2b(acc[i][j][1]);
          u.z = f2b(acc[i][j][2]); u.w = f2b(acc[i][j][3]);
          *(ushort4*)(&MT[(j * 16 + l16) * XT_STR + (at0 + i) * 16 + quad * 4]) = u;
        }
    }
    __syncthreads();  // S4: Tt ready

    // ---- phase 4: Yt[q][o] += Tt . Wov_h, MFMA acc in regs ----
    {
      const ushort_t* wh = Wovbf + h * 65536;
#pragma unroll
      for (int k = 0; k < 8; ++k) {
        bf16x8 af[4], bf[2];
#pragma unroll
        for (int j = 0; j < 4; ++j)
          af[j] = *(const bf16x8*)(&MT[(j * 16 + l16) * XT_STR + k * 32 + quad * 8]);
#pragma unroll
        for (int i = 0; i < 2; ++i)
          bf[i] = *(const bf16x8*)(wh + ((at0 + i) * 16 + l16) * 256 + k * 32 + quad * 8);
#pragma unroll
        for (int i = 0; i < 2; ++i)
#pragma unroll
          for (int j = 0; j < 4; ++j)
            yac[i][j] = __builtin_amdgcn_mfma_f32_16x16x32_bf16(af[j], bf[i], yac[i][j], 0, 0, 0);
      }
    }
  }

  // ---- epilogue: Y + cvec -> out[n][o][pos] (rolled coords) ----
  float* obase = out + n * (256 * 3136);
#pragma unroll
  for (int i = 0; i < 2; ++i) {
    const int o = (at0 + i) * 16 + l16;
    const float cv = cvec[o];
#pragma unroll
    for (int j = 0; j < 4; ++j) {
#pragma unroll
      for (int r = 0; r < 4; ++r) {
        int q = j * 16 + quad * 4 + r;
        if (q < 49) {
          int wi = div7(q), wj = q - wi * 7;
          int pos = (gi * 7 + wi) * 56 + gj * 7 + wj;
          obase[o * 3136 + pos] = yac[i][j][r] + cv;
        }
      }
    }
  }
}

extern "C" void kernel_launch(void* const* d_in, const int* in_sizes, int n_in,
                              void* d_out, int out_size, void* d_ws, size_t ws_size,
                              hipStream_t stream) {
  (void)in_sizes; (void)n_in; (void)out_size; (void)ws_size;
  const float* X  = (const float*)d_in[0];
  const float* Wk = (const float*)d_in[1];
  const float* bk = (const float*)d_in[2];
  const float* Wq = (const float*)d_in[3];
  const float* bq = (const float*)d_in[4];
  const float* Wv = (const float*)d_in[5];
  const float* bv = (const float*)d_in[6];
  const float* Wo = (const float*)d_in[7];
  const float* bo = (const float*)d_in[8];
  const float* rc = (const float*)d_in[9];

  ushort_t* Gbf   = (ushort_t*)d_ws;            // 8*256*256 bf16 = 1 MB
  ushort_t* Wovbf = Gbf + 524288;               // 1 MB
  float* fws = (float*)((char*)d_ws + 2097152);
  float* w1 = fws;            // 2048
  float* w2 = fws + 2048;     // 2048
  float* c0 = fws + 4096;     // 8
  float* cv = fws + 4104;     // 256
  float* out = (float*)d_out;

  k_gw  <<<dim3(1024), dim3(256), 0, stream>>>(Wk, Wq, Wo, Wv, Gbf, Wovbf);
  k_vecs<<<dim3(9),    dim3(256), 0, stream>>>(Wk, Wq, bk, bq, Wo, bv, bo, w1, w2, c0, cv);
  k_attn<<<dim3(NBATCH * 64), dim3(512), 0, stream>>>(X, rc, Gbf, Wovbf, w1, w2, c0, cv, out);
}

// Round 4
// 417.960 us; speedup vs baseline: 7.5918x; 1.0747x over previous
//
#include <hip/hip_runtime.h>
#include <hip/hip_bf16.h>

// Swin window MHSA, MI355X, MFMA version, round 4.
// Algebra: S = X^T G X + rank-1 bias, Y = sum_h Wov_h (X wmap_h) + cvec,
// G_h = Wk_h^T Wq_h, Wov_h = Wo_h Wv_h precomputed as bf16 in d_ws.
// One block per (batch, window); 512 threads = 8 waves.
// R4: LDS 123->78 KB (Xs dropped -> phase-T A-frags in registers; scores bf16)
// so 2 blocks/CU co-reside and overlap barrier stalls. Prep merged to 1 kernel.

#define NBATCH 8
#define NHEAD  8

typedef unsigned short ushort_t;
typedef __attribute__((ext_vector_type(8))) short bf16x8;   // 8 bf16 = 4 VGPR
typedef __attribute__((ext_vector_type(4))) float f32x4;    // MFMA acc

__device__ __forceinline__ float b2f(ushort_t u) {
  union { unsigned int i; float f; } v; v.i = ((unsigned int)u) << 16; return v.f;
}
__device__ __forceinline__ ushort_t f2b(float f) {
  union { float f; unsigned int u; } v; v.f = f;
  unsigned int u = v.u;
  return (ushort_t)((u + 0x7FFFu + ((u >> 16) & 1u)) >> 16);
}
__device__ __forceinline__ int regof(int y) { return (y < 49) ? 0 : ((y < 53) ? 1 : 2); }
__device__ __forceinline__ int div7(int t) { return (t * 37) >> 8; }  // t/7 for t<64

// ---- merged prep kernel ----
// blocks 0..511:    Gbf[h][a][b]   = sum_dd Wk[h,dd,a]*Wq[h,dd,b]
// blocks 512..1023: Wovbf[h][o][d] = sum_dd Wo[o][h,dd]*Wv[h,dd,d]
// blocks 1024..1031 (h): w1_h[b]=bk_h.Wq_h[:,b], w2_h[a]=bq_h.Wk_h[:,a], c0_h
// blocks 1032..1287 (o): cvec[o]=bo[o]+sum_hd Wo[o][hd]*bv[hd]  (coalesced)
__global__ void k_prep(const float* __restrict__ Wk, const float* __restrict__ Wq,
                       const float* __restrict__ Wo, const float* __restrict__ Wv,
                       const float* __restrict__ bk, const float* __restrict__ bq,
                       const float* __restrict__ bv, const float* __restrict__ bo,
                       ushort_t* __restrict__ Gbf, ushort_t* __restrict__ Wovbf,
                       float* __restrict__ w1, float* __restrict__ w2,
                       float* __restrict__ c0, float* __restrict__ cvec) {
  __shared__ float red[4];
  int blk = blockIdx.x, t = threadIdx.x;
  if (blk < 512) {
    int h = blk >> 6, b0 = (blk & 63) << 2, a = t;
    const float* wkh = Wk + h * 65536;
    const float* wqh = Wq + h * 65536;
    float a0 = 0.f, a1 = 0.f, a2 = 0.f, a3 = 0.f;
    for (int dd = 0; dd < 256; ++dd) {
      float wk = wkh[dd * 256 + a];
      float4 w4 = *(const float4*)(wqh + dd * 256 + b0);
      a0 += wk * w4.x; a1 += wk * w4.y; a2 += wk * w4.z; a3 += wk * w4.w;
    }
    ushort4 u; u.x = f2b(a0); u.y = f2b(a1); u.z = f2b(a2); u.w = f2b(a3);
    *(ushort4*)(Gbf + h * 65536 + a * 256 + b0) = u;
  } else if (blk < 1024) {
    int bb = blk - 512;
    int h = bb >> 6, d0 = (bb & 63) << 2, o = t;
    const float* wob = Wo + o * 2048 + h * 256;
    float a0 = 0.f, a1 = 0.f, a2 = 0.f, a3 = 0.f;
    for (int dd = 0; dd < 256; ++dd) {
      float wo = wob[dd];
      float4 w4 = *(const float4*)(Wv + (h * 256 + dd) * 256 + d0);
      a0 += wo * w4.x; a1 += wo * w4.y; a2 += wo * w4.z; a3 += wo * w4.w;
    }
    ushort4 u; u.x = f2b(a0); u.y = f2b(a1); u.z = f2b(a2); u.w = f2b(a3);
    *(ushort4*)(Wovbf + h * 65536 + o * 256 + d0) = u;
  } else if (blk < 1032) {
    int h = blk - 1024;
    float s1 = 0.f, s2 = 0.f;
    for (int dd = 0; dd < 256; ++dd) {
      s1 += bk[h * 256 + dd] * Wq[(h * 256 + dd) * 256 + t];
      s2 += bq[h * 256 + dd] * Wk[(h * 256 + dd) * 256 + t];
    }
    w1[h * 256 + t] = s1;
    w2[h * 256 + t] = s2;
    if (t == 0) {
      float c = 0.f;
      for (int dd = 0; dd < 256; ++dd) c += bk[h * 256 + dd] * bq[h * 256 + dd];
      c0[h] = c;
    }
  } else {
    int o = blk - 1032;
    const float* wob = Wo + o * 2048;
    float acc = 0.f;
#pragma unroll
    for (int j = 0; j < 8; ++j) acc += wob[j * 256 + t] * bv[j * 256 + t];
#pragma unroll
    for (int s = 1; s < 64; s <<= 1) acc += __shfl_xor(acc, s);
    if ((t & 63) == 0) red[t >> 6] = acc;
    __syncthreads();
    if (t == 0) cvec[o] = bo[o] + red[0] + red[1] + red[2] + red[3];
  }
}

// ---- main fused MFMA kernel: one block per (n, window), 512 threads ----
#define XT_STR  264   // Xt/MT [64 tok][264] bf16 (256 d + pad)
#define STB_STR 72    // StB [64 q][72 p] bf16 scores / wmap^T

__global__ __launch_bounds__(512, 4) void k_attn(
    const float* __restrict__ X,          // [8][256][3136] fp32
    const float* __restrict__ relc,       // [169][8] fp32
    const ushort_t* __restrict__ Gbf,     // [8][256 a][256 b] bf16
    const ushort_t* __restrict__ Wovbf,   // [8][256 o][256 d] bf16
    const float* __restrict__ w1, const float* __restrict__ w2,
    const float* __restrict__ c0v, const float* __restrict__ cvec,
    float* __restrict__ out) {

  __shared__ ushort_t Xt[64 * XT_STR];    // [p|q][d]
  __shared__ ushort_t MT[64 * XT_STR];    // Mt[q][a] then Tt[q][d]
  __shared__ ushort_t StB[64 * STB_STR];  // scores [q][p] bf16; wmap^T in-place
  __shared__ float    aqs[64];
  __shared__ float    bps[64];
  __shared__ float    relL[169];

  const int tid  = threadIdx.x;
  const int wave = tid >> 6;
  const int lane = tid & 63;
  const int quad = lane >> 4;
  const int l16  = lane & 15;
  const int n  = blockIdx.x >> 6;
  const int g  = blockIdx.x & 63;
  const int gi = g >> 3, gj = g & 7;

  // ---- prologue: gather rolled window -> Xt[p][d] ----
  {
    const int d = tid >> 1, half = tid & 1;
    const int c = d >> 4, p1 = (d >> 2) & 3, p2 = d & 3;
    const float* xin = X + n * (256 * 3136);
    const int pbeg = half * 25, pend = half ? 49 : 25;
    for (int p = pbeg; p < pend; ++p) {
      int wi = div7(p), wj = p - wi * 7;
      int y = (gi * 7 + wi) * 4 + p1;
      int x = (gj * 7 + wj) * 4 + p2;
      int ys = y - 3; if (ys < 0) ys += 224;
      int xs = x - 3; if (xs < 0) xs += 224;
      int ds = c * 16 + (ys & 3) * 4 + (xs & 3);
      int ts = (ys >> 2) * 56 + (xs >> 2);
      Xt[p * XT_STR + d] = f2b(xin[ds * 3136 + ts]);
    }
  }
  // zero Xt pad rows p=49..63
  for (int i = tid; i < 15 * XT_STR; i += 512) Xt[49 * XT_STR + i] = 0;
  __syncthreads();

  const int at0 = wave * 2;  // a/d/o tile pair owned by this wave (phases 2,T,4)

  // ---- phase-T A-frags (X[d][p]) live in registers for the whole kernel ----
  bf16x8 xfr[2][2];
#pragma unroll
  for (int i = 0; i < 2; ++i) {
    const int d = (at0 + i) * 16 + l16;
#pragma unroll
    for (int k = 0; k < 2; ++k)
#pragma unroll
      for (int j = 0; j < 8; ++j)
        xfr[i][k][j] = (short)Xt[(k * 32 + quad * 8 + j) * XT_STR + d];
  }

  // Yt accumulators: o-tiles {2*wave, 2*wave+1} x q-tiles 0..3
  f32x4 yac[2][4];
#pragma unroll
  for (int i = 0; i < 2; ++i)
#pragma unroll
    for (int j = 0; j < 4; ++j) yac[i][j] = (f32x4){0.f, 0.f, 0.f, 0.f};

  for (int h = 0; h < NHEAD; ++h) {
    __syncthreads();  // S0: prev phase4 MT-reads done; MT/StB free; Xt stable

    // ---- rel table + rank-1 bias terms ----
    if (tid < 169) relL[tid] = relc[tid * 8 + h];
    {
      const int q = tid >> 3, sub = tid & 7;
      const float* w1h = w1 + h * 256;
      const float* w2h = w2 + h * 256;
      float sa = 0.f, sb = 0.f;
      for (int i = 0; i < 32; ++i) {
        int dd = sub * 32 + i;
        float xv = b2f(Xt[q * XT_STR + dd]);
        sa += w1h[dd] * xv;
        sb += w2h[dd] * xv;
      }
      sa += __shfl_xor(sa, 1); sb += __shfl_xor(sb, 1);
      sa += __shfl_xor(sa, 2); sb += __shfl_xor(sb, 2);
      sa += __shfl_xor(sa, 4); sb += __shfl_xor(sb, 4);
      if (sub == 0) { aqs[q] = sa; bps[q] = sb; }
    }

    // ---- phase 2: Mt[q][a] = (G_h^T X)[a][q], MFMA ----
    {
      const ushort_t* gh = Gbf + h * 65536;
      f32x4 acc[2][4];
#pragma unroll
      for (int i = 0; i < 2; ++i)
#pragma unroll
        for (int j = 0; j < 4; ++j) acc[i][j] = (f32x4){0.f, 0.f, 0.f, 0.f};
#pragma unroll
      for (int k = 0; k < 8; ++k) {
        bf16x8 af[2], bf[4];
#pragma unroll
        for (int i = 0; i < 2; ++i)
          af[i] = *(const bf16x8*)(gh + ((at0 + i) * 16 + l16) * 256 + k * 32 + quad * 8);
#pragma unroll
        for (int j = 0; j < 4; ++j)
          bf[j] = *(const bf16x8*)(&Xt[(j * 16 + l16) * XT_STR + k * 32 + quad * 8]);
#pragma unroll
        for (int i = 0; i < 2; ++i)
#pragma unroll
          for (int j = 0; j < 4; ++j)
            acc[i][j] = __builtin_amdgcn_mfma_f32_16x16x32_bf16(af[i], bf[j], acc[i][j], 0, 0, 0);
      }
#pragma unroll
      for (int i = 0; i < 2; ++i)
#pragma unroll
        for (int j = 0; j < 4; ++j) {
          ushort4 u;
          u.x = f2b(acc[i][j][0]); u.y = f2b(acc[i][j][1]);
          u.z = f2b(acc[i][j][2]); u.w = f2b(acc[i][j][3]);
          *(ushort4*)(&MT[(j * 16 + l16) * XT_STR + (at0 + i) * 16 + quad * 4]) = u;
        }
    }
    __syncthreads();  // S1: Mt + biases ready

    // ---- phase 3: S[p][q] = X^T M + biases -> StB[q][p] bf16 ----
    {
      const int ptile = wave & 3;
      const int qt0 = (wave >> 2) * 2;
      f32x4 acc[2];
#pragma unroll
      for (int j = 0; j < 2; ++j) acc[j] = (f32x4){0.f, 0.f, 0.f, 0.f};
#pragma unroll
      for (int k = 0; k < 8; ++k) {
        bf16x8 af = *(const bf16x8*)(&Xt[(ptile * 16 + l16) * XT_STR + k * 32 + quad * 8]);
#pragma unroll
        for (int j = 0; j < 2; ++j) {
          bf16x8 bf = *(const bf16x8*)(&MT[((qt0 + j) * 16 + l16) * XT_STR + k * 32 + quad * 8]);
          acc[j] = __builtin_amdgcn_mfma_f32_16x16x32_bf16(af, bf, acc[j], 0, 0, 0);
        }
      }
      const float c0h = c0v[h];
#pragma unroll
      for (int j = 0; j < 2; ++j) {
        const int q = (qt0 + j) * 16 + l16;
        const int qq = (q < 49) ? q : 48;        // clamp pad rows (never output)
        const int yq = div7(qq), xq = qq - yq * 7;
        const int fq = regof(gi * 7 + yq) * 3 + regof(gj * 7 + xq);
        const float aqv = aqs[q];
        ushort4 sv;
        ushort_t* svp = &sv.x;
#pragma unroll
        for (int r = 0; r < 4; ++r) {
          int p = ptile * 16 + quad * 4 + r;
          float val = -1e30f;
          if (p < 49) {
            int yp = div7(p), xp = p - yp * 7;
            int fp = regof(gi * 7 + yp) * 3 + regof(gj * 7 + xp);
            float rel = relL[(yp - yq + 6) + 13 * (xp - xq + 6)];
            val = (acc[j][r] + aqv + bps[p] + c0h) * 0.0625f + rel;
            if (fp != fq) val -= 100.f;
          }
          svp[r] = f2b(val);
        }
        *(ushort4*)(&StB[q * STB_STR + ptile * 16 + quad * 4]) = sv;
      }
    }
    __syncthreads();  // S2: StB ready

    // ---- softmax over p per row q; wmap^T bf16 written in-place ----
    {
      const int q = tid >> 3, sub = tid & 7, p0 = sub * 8;
      ushort_t* row = &StB[q * STB_STR];
      bf16x8 in8 = *(const bf16x8*)(&row[p0]);
      float v[8];
#pragma unroll
      for (int i = 0; i < 8; ++i) v[i] = b2f((ushort_t)in8[i]);
      float m = v[0];
#pragma unroll
      for (int i = 1; i < 8; ++i) m = fmaxf(m, v[i]);
      m = fmaxf(m, __shfl_xor(m, 1));
      m = fmaxf(m, __shfl_xor(m, 2));
      m = fmaxf(m, __shfl_xor(m, 4));
      float s = 0.f;
#pragma unroll
      for (int i = 0; i < 8; ++i) { v[i] = __expf(v[i] - m); s += v[i]; }
      s += __shfl_xor(s, 1);
      s += __shfl_xor(s, 2);
      s += __shfl_xor(s, 4);
      float inv = 1.f / s;
      bf16x8 w8;
#pragma unroll
      for (int i = 0; i < 8; ++i) w8[i] = (short)f2b(v[i] * inv);
      *(bf16x8*)(&row[p0]) = w8;
    }
    __syncthreads();  // S3: wmap^T ready

    // ---- phase T: Tt[q][d] = (X wmap)[d][q], MFMA (A-frags from registers) ----
    {
      f32x4 acc[2][4];
#pragma unroll
      for (int i = 0; i < 2; ++i)
#pragma unroll
        for (int j = 0; j < 4; ++j) acc[i][j] = (f32x4){0.f, 0.f, 0.f, 0.f};
#pragma unroll
      for (int k = 0; k < 2; ++k) {
        bf16x8 bf[4];
#pragma unroll
        for (int j = 0; j < 4; ++j)
          bf[j] = *(const bf16x8*)(&StB[(j * 16 + l16) * STB_STR + k * 32 + quad * 8]);
#pragma unroll
        for (int i = 0; i < 2; ++i)
#pragma unroll
          for (int j = 0; j < 4; ++j)
            acc[i][j] = __builtin_amdgcn_mfma_f32_16x16x32_bf16(xfr[i][k], bf[j], acc[i][j], 0, 0, 0);
      }
#pragma unroll
      for (int i = 0; i < 2; ++i)
#pragma unroll
        for (int j = 0; j < 4; ++j) {
          ushort4 u;
          u.x = f2b(acc[i][j][0]); u.y = f2b(acc[i][j][1]);
          u.z = f2b(acc[i][j][2]); u.w = f2b(acc[i][j][3]);
          *(ushort4*)(&MT[(j * 16 + l16) * XT_STR + (at0 + i) * 16 + quad * 4]) = u;
        }
    }
    __syncthreads();  // S4: Tt ready

    // ---- phase 4: Yt[q][o] += Tt . Wov_h, MFMA acc in regs ----
    {
      const ushort_t* wh = Wovbf + h * 65536;
#pragma unroll
      for (int k = 0; k < 8; ++k) {
        bf16x8 af[4], bf[2];
#pragma unroll
        for (int j = 0; j < 4; ++j)
          af[j] = *(const bf16x8*)(&MT[(j * 16 + l16) * XT_STR + k * 32 + quad * 8]);
#pragma unroll
        for (int i = 0; i < 2; ++i)
          bf[i] = *(const bf16x8*)(wh + ((at0 + i) * 16 + l16) * 256 + k * 32 + quad * 8);
#pragma unroll
        for (int i = 0; i < 2; ++i)
#pragma unroll
          for (int j = 0; j < 4; ++j)
            yac[i][j] = __builtin_amdgcn_mfma_f32_16x16x32_bf16(af[j], bf[i], yac[i][j], 0, 0, 0);
      }
    }
  }

  // ---- epilogue: Y + cvec -> out[n][o][pos] (rolled coords) ----
  float* obase = out + n * (256 * 3136);
#pragma unroll
  for (int i = 0; i < 2; ++i) {
    const int o = (at0 + i) * 16 + l16;
    const float cv = cvec[o];
#pragma unroll
    for (int j = 0; j < 4; ++j) {
#pragma unroll
      for (int r = 0; r < 4; ++r) {
        int q = j * 16 + quad * 4 + r;
        if (q < 49) {
          int wi = div7(q), wj = q - wi * 7;
          int pos = (gi * 7 + wi) * 56 + gj * 7 + wj;
          obase[o * 3136 + pos] = yac[i][j][r] + cv;
        }
      }
    }
  }
}

extern "C" void kernel_launch(void* const* d_in, const int* in_sizes, int n_in,
                              void* d_out, int out_size, void* d_ws, size_t ws_size,
                              hipStream_t stream) {
  (void)in_sizes; (void)n_in; (void)out_size; (void)ws_size;
  const float* X  = (const float*)d_in[0];
  const float* Wk = (const float*)d_in[1];
  const float* bk = (const float*)d_in[2];
  const float* Wq = (const float*)d_in[3];
  const float* bq = (const float*)d_in[4];
  const float* Wv = (const float*)d_in[5];
  const float* bv = (const float*)d_in[6];
  const float* Wo = (const float*)d_in[7];
  const float* bo = (const float*)d_in[8];
  const float* rc = (const float*)d_in[9];

  ushort_t* Gbf   = (ushort_t*)d_ws;            // 8*256*256 bf16 = 1 MB
  ushort_t* Wovbf = Gbf + 524288;               // 1 MB
  float* fws = (float*)((char*)d_ws + 2097152);
  float* w1 = fws;            // 2048
  float* w2 = fws + 2048;     // 2048
  float* c0 = fws + 4096;     // 8
  float* cv = fws + 4104;     // 256
  float* out = (float*)d_out;

  k_prep<<<dim3(1288), dim3(256), 0, stream>>>(Wk, Wq, Wo, Wv, bk, bq, bv, bo,
                                               Gbf, Wovbf, w1, w2, c0, cv);
  k_attn<<<dim3(NBATCH * 64), dim3(512), 0, stream>>>(X, rc, Gbf, Wovbf, w1, w2, c0, cv, out);
}

// Round 5
// 341.057 us; speedup vs baseline: 9.3037x; 1.2255x over previous
//
#include <hip/hip_runtime.h>
#include <hip/hip_bf16.h>

// Swin window MHSA, MI355X, round 5: split into throughput-shaped kernels.
//   k_prep : Aext[2176x256]=G'(+w1/w2 rows), Wov3[256x2048], cvec, relL2(+c0)
//   k_conv : X fp32 -> rolled bf16 Xroll[n][3200][256]
//   k_gemm1: M_T[n][t][a'] = Xroll . Aext^T           (MFMA GEMM)
//   k_attn2: per (n,window): S=Xp.M, softmax, T=X.wmap; T overwrites M in-place
//   k_gemm3: out[n][o][t] = Wov3 . T_T^T + cvec       (MFMA GEMM)

#define NBATCH 8
#define MSTR   2176           // M_T / T_T row stride (a'-dim, 17 tiles of 128)
#define TROWS  3200           // padded token rows (25 tiles of 128)

typedef unsigned short ushort_t;
typedef __attribute__((ext_vector_type(8))) short bf16x8;   // 8 bf16 = 4 VGPR
typedef __attribute__((ext_vector_type(8))) unsigned short u16x8;
typedef __attribute__((ext_vector_type(4))) float f32x4;    // MFMA acc

__device__ __forceinline__ float b2f(ushort_t u) {
  union { unsigned int i; float f; } v; v.i = ((unsigned int)u) << 16; return v.f;
}
__device__ __forceinline__ ushort_t f2b(float f) {
  union { float f; unsigned int u; } v; v.f = f;
  unsigned int u = v.u;
  return (ushort_t)((u + 0x7FFFu + ((u >> 16) & 1u)) >> 16);
}
__device__ __forceinline__ int regof(int y) { return (y < 49) ? 0 : ((y < 53) ? 1 : 2); }
__device__ __forceinline__ int div7(int t) { return (t * 37) >> 8; }  // t/7, t<64
__device__ __forceinline__ int tmap(int p, int gi, int gj) {
  int wi = div7(p); return (gi * 7 + wi) * 56 + gj * 7 + (p - wi * 7);
}
__device__ __forceinline__ ushort4 pack4(f32x4 a) {
  ushort4 u; u.x = f2b(a[0]); u.y = f2b(a[1]); u.z = f2b(a[2]); u.w = f2b(a[3]);
  return u;
}

// ================= prep =================
__global__ void k_prep(const float* __restrict__ Wk, const float* __restrict__ Wq,
                       const float* __restrict__ Wo, const float* __restrict__ Wv,
                       const float* __restrict__ bk, const float* __restrict__ bq,
                       const float* __restrict__ bv, const float* __restrict__ bo,
                       const float* __restrict__ relc,
                       ushort_t* __restrict__ Aext, ushort_t* __restrict__ Wov3,
                       float* __restrict__ cvec, float* __restrict__ relL2) {
  __shared__ float red[8];
  int blk = blockIdx.x, t = threadIdx.x;
  if (blk < 512) {
    // Aext[h*256+a][b] = sum_dd Wk[h,dd,a]*Wq[h,dd,b]
    int h = blk >> 6, b0 = (blk & 63) << 2, a = t;
    const float* wkh = Wk + h * 65536;
    const float* wqh = Wq + h * 65536;
    float a0 = 0.f, a1 = 0.f, a2 = 0.f, a3 = 0.f;
    for (int dd = 0; dd < 256; ++dd) {
      float wk = wkh[dd * 256 + a];
      float4 w4 = *(const float4*)(wqh + dd * 256 + b0);
      a0 += wk * w4.x; a1 += wk * w4.y; a2 += wk * w4.z; a3 += wk * w4.w;
    }
    ushort4 u; u.x = f2b(a0); u.y = f2b(a1); u.z = f2b(a2); u.w = f2b(a3);
    *(ushort4*)(Aext + (h * 256 + a) * 256 + b0) = u;
  } else if (blk < 1024) {
    // Wov3[o][h*256+d] = sum_dd Wo[o][h*256+dd]*Wv[h,dd,d]; threads = d
    int bb = blk - 512;
    int h = bb >> 6, o0 = (bb & 63) << 2, d = t;
    float a0 = 0.f, a1 = 0.f, a2 = 0.f, a3 = 0.f;
    for (int dd = 0; dd < 256; ++dd) {
      float wv = Wv[(h * 256 + dd) * 256 + d];
      a0 += Wo[(o0 + 0) * 2048 + h * 256 + dd] * wv;
      a1 += Wo[(o0 + 1) * 2048 + h * 256 + dd] * wv;
      a2 += Wo[(o0 + 2) * 2048 + h * 256 + dd] * wv;
      a3 += Wo[(o0 + 3) * 2048 + h * 256 + dd] * wv;
    }
    Wov3[(o0 + 0) * 2048 + h * 256 + d] = f2b(a0);
    Wov3[(o0 + 1) * 2048 + h * 256 + d] = f2b(a1);
    Wov3[(o0 + 2) * 2048 + h * 256 + d] = f2b(a2);
    Wov3[(o0 + 3) * 2048 + h * 256 + d] = f2b(a3);
  } else if (blk < 1032) {
    // rank-1 bias rows: Aext[2048+h] = w1_h, Aext[2056+h] = w2_h
    int h = blk - 1024;
    float s1 = 0.f, s2 = 0.f;
    for (int dd = 0; dd < 256; ++dd) {
      s1 += bk[h * 256 + dd] * Wq[(h * 256 + dd) * 256 + t];
      s2 += bq[h * 256 + dd] * Wk[(h * 256 + dd) * 256 + t];
    }
    Aext[(2048 + h) * 256 + t] = f2b(s1);
    Aext[(2056 + h) * 256 + t] = f2b(s2);
  } else if (blk == 1032) {
    // zero Aext rows 2064..2175
    for (int i = t; i < 112 * 256 / 8; i += 256)
      *(u16x8*)(Aext + 2064 * 256 + i * 8) = (u16x8){0,0,0,0,0,0,0,0};
  } else if (blk < 1289) {
    // cvec[o] = bo[o] + sum_hd Wo[o][hd]*bv[hd]
    int o = blk - 1033;
    const float* wob = Wo + o * 2048;
    float acc = 0.f;
#pragma unroll
    for (int j = 0; j < 8; ++j) acc += wob[j * 256 + t] * bv[j * 256 + t];
#pragma unroll
    for (int s = 1; s < 64; s <<= 1) acc += __shfl_xor(acc, s);
    if ((t & 63) == 0) red[t >> 6] = acc;
    __syncthreads();
    if (t == 0) cvec[o] = bo[o] + red[0] + red[1] + red[2] + red[3];
  } else {
    // relL2[h][idx] = relc[idx][h] + (bk_h.bq_h)/16
    if (t < 8) {
      float c = 0.f;
      for (int dd = 0; dd < 256; ++dd) c += bk[t * 256 + dd] * bq[t * 256 + dd];
      red[t] = c * 0.0625f;
    }
    __syncthreads();
    for (int i = t; i < 8 * 169; i += 256) {
      int h = i / 169, idx = i - h * 169;
      relL2[i] = relc[idx * 8 + h] + red[h];
    }
  }
}

// ================= conv: rolled gather X -> Xroll bf16 =================
__global__ void k_conv(const float* __restrict__ X, ushort_t* __restrict__ Xroll) {
  const int n = blockIdx.x / 57, y = blockIdx.x % 57;
  const int tid = threadIdx.x;
  ushort_t* xr = Xroll + (size_t)n * TROWS * 256;
  if (y == 56) {  // zero pad rows 3136..3199
    for (int i = tid; i < 64 * 256 / 8; i += 256)
      *(u16x8*)(xr + 3136 * 256 + i * 8) = (u16x8){0,0,0,0,0,0,0,0};
    return;
  }
  const int wave = tid >> 6, x = tid & 63;
  const float* xin = X + (size_t)n * 256 * 3136;
  const int ty_m = (y == 0) ? 55 : y - 1;
  const int tx_m = (x == 0) ? 55 : x - 1;
  for (int dd = 0; dd < 64; ++dd) {
    int d = wave * 64 + dd;
    int c = d >> 4, p1 = (d >> 2) & 3, p2 = d & 3;
    int sp = c * 16 + (((p1 + 1) & 3) << 2) + ((p2 + 1) & 3);
    int ty = (p1 == 3) ? y : ty_m;
    int tx = (p2 == 3) ? x : tx_m;
    if (x < 56)
      xr[(y * 56 + x) * 256 + d] = f2b(xin[sp * 3136 + ty * 56 + tx]);
  }
}

// ================= gemm1: M_T[t][a'] = Xroll . Aext^T =================
__global__ __launch_bounds__(256, 2) void k_gemm1(
    const ushort_t* __restrict__ Xroll, const ushort_t* __restrict__ Aext,
    ushort_t* __restrict__ MT) {
  __shared__ ushort_t Asm[128 * 72];
  __shared__ ushort_t Bsm[128 * 72];
  const int bx = blockIdx.x;
  const int n = bx / 425, r = bx % 425;
  const int tt = r / 17, aa = r % 17;
  const int a0 = aa * 128, t0 = tt * 128;
  const int tid = threadIdx.x, wave = tid >> 6, lane = tid & 63;
  const int quad = lane >> 4, l16 = lane & 15;
  const int wa = wave >> 1, wt = wave & 1;
  const ushort_t* Xn = Xroll + (size_t)n * TROWS * 256;
  ushort_t* Mn = MT + (size_t)n * TROWS * MSTR;

  const int sr = tid >> 1, sc = (tid & 1) * 4;  // staging: row, chunk-base
  bf16x8 ra[4], rb[4];
#pragma unroll
  for (int i = 0; i < 4; ++i) {
    ra[i] = *(const bf16x8*)(Aext + (a0 + sr) * 256 + (sc + i) * 8);
    rb[i] = *(const bf16x8*)(Xn + (t0 + sr) * 256 + (sc + i) * 8);
  }

  f32x4 acc[4][4];
#pragma unroll
  for (int i = 0; i < 4; ++i)
#pragma unroll
    for (int j = 0; j < 4; ++j) acc[i][j] = (f32x4){0.f, 0.f, 0.f, 0.f};

  for (int kit = 0; kit < 4; ++kit) {
#pragma unroll
    for (int i = 0; i < 4; ++i) {
      *(bf16x8*)(&Asm[sr * 72 + (sc + i) * 8]) = ra[i];
      *(bf16x8*)(&Bsm[sr * 72 + (sc + i) * 8]) = rb[i];
    }
    __syncthreads();
    if (kit < 3) {
      int k0 = (kit + 1) * 64;
#pragma unroll
      for (int i = 0; i < 4; ++i) {
        ra[i] = *(const bf16x8*)(Aext + (a0 + sr) * 256 + k0 + (sc + i) * 8);
        rb[i] = *(const bf16x8*)(Xn + (t0 + sr) * 256 + k0 + (sc + i) * 8);
      }
    }
#pragma unroll
    for (int kk = 0; kk < 2; ++kk) {
      bf16x8 af[4], bf[4];
#pragma unroll
      for (int i = 0; i < 4; ++i)
        af[i] = *(const bf16x8*)(&Asm[(wa * 64 + i * 16 + l16) * 72 + kk * 32 + quad * 8]);
#pragma unroll
      for (int j = 0; j < 4; ++j)
        bf[j] = *(const bf16x8*)(&Bsm[(wt * 64 + j * 16 + l16) * 72 + kk * 32 + quad * 8]);
#pragma unroll
      for (int i = 0; i < 4; ++i)
#pragma unroll
        for (int j = 0; j < 4; ++j)
          acc[i][j] = __builtin_amdgcn_mfma_f32_16x16x32_bf16(af[i], bf[j], acc[i][j], 0, 0, 0);
    }
    __syncthreads();
  }
  // store C transposed: M_T[t][a']
#pragma unroll
  for (int i = 0; i < 4; ++i)
#pragma unroll
    for (int j = 0; j < 4; ++j) {
      int tg = t0 + wt * 64 + j * 16 + l16;
      int ag = a0 + wa * 64 + i * 16 + quad * 4;
      *(ushort4*)(Mn + (size_t)tg * MSTR + ag) = pack4(acc[i][j]);
    }
}

// ================= attn2: per (n,window); 2 heads via wave-groups =========
#define XP_STR 264
__global__ __launch_bounds__(512, 4) void k_attn2(
    const ushort_t* __restrict__ Xroll, ushort_t* __restrict__ MT,
    const float* __restrict__ relL2) {
  __shared__ ushort_t Xp[64 * XP_STR];
  __shared__ ushort_t StB[2][64 * 72];
  __shared__ float aqsL[8 * 64];
  __shared__ float bpsL[8 * 64];
  __shared__ float relLh[8 * 169];

  const int tid = threadIdx.x;
  const int wave = tid >> 6, lane = tid & 63;
  const int quad = lane >> 4, l16 = lane & 15;
  const int group = wave >> 2, wv = wave & 3;
  const int n = blockIdx.x >> 6, g = blockIdx.x & 63;
  const int gi = g >> 3, gj = g & 7;
  const ushort_t* Xn = Xroll + (size_t)n * TROWS * 256;
  ushort_t* Mn = MT + (size_t)n * TROWS * MSTR;

  // ---- prologue ----
  {
    const int p = tid & 63, cg = tid >> 6;
    if (p < 49) {
      int t = tmap(p, gi, gj);
#pragma unroll
      for (int i = 0; i < 4; ++i)
        *(u16x8*)(&Xp[p * XP_STR + (cg * 4 + i) * 8]) =
            *(const u16x8*)(Xn + t * 256 + (cg * 4 + i) * 8);
    } else {
#pragma unroll
      for (int i = 0; i < 4; ++i)
        *(u16x8*)(&Xp[p * XP_STR + (cg * 4 + i) * 8]) = (u16x8){0,0,0,0,0,0,0,0};
    }
  }
  for (int i = tid; i < 8 * 169; i += 512) relLh[i] = relL2[i];
  {
    const int h = tid >> 6, q = tid & 63;
    int qq = (q < 49) ? q : 48;
    int t = tmap(qq, gi, gj);
    aqsL[h * 64 + q] = b2f(Mn[(size_t)t * MSTR + 2048 + h]);
    bpsL[h * 64 + q] = b2f(Mn[(size_t)t * MSTR + 2056 + h]);
  }
  __syncthreads();

  // phase-T A-frags in registers (head-independent): d-tiles wv*4..wv*4+3
  bf16x8 xfr[4][2];
#pragma unroll
  for (int dt = 0; dt < 4; ++dt) {
    const int d = (wv * 4 + dt) * 16 + l16;
#pragma unroll
    for (int kk = 0; kk < 2; ++kk)
#pragma unroll
      for (int j = 0; j < 8; ++j)
        xfr[dt][kk][j] = (short)Xp[(kk * 32 + quad * 8 + j) * XP_STR + d];
  }

  // per-lane S B-operand base: row t(q), q = wv*16+l16
  const int q = wv * 16 + l16;
  const int qq = (q < 49) ? q : 48;
  const int tq = tmap(qq, gi, gj);
  const ushort_t* Mbase = Mn + (size_t)tq * MSTR + quad * 8;
  const int yq = div7(qq), xq = qq - yq * 7;
  const int fq = regof(gi * 7 + yq) * 3 + regof(gj * 7 + xq);

  for (int hh = 0; hh < 4; ++hh) {
    const int h = hh * 2 + group;
    // ---- S: MFMA, A from Xp LDS, B streamed from global M ----
    f32x4 sacc[4];
#pragma unroll
    for (int pt = 0; pt < 4; ++pt) sacc[pt] = (f32x4){0.f, 0.f, 0.f, 0.f};
    const ushort_t* mrow = Mbase + h * 256;
#pragma unroll
    for (int kk = 0; kk < 8; ++kk) {
      bf16x8 bfm = *(const bf16x8*)(mrow + kk * 32);
#pragma unroll
      for (int pt = 0; pt < 4; ++pt) {
        bf16x8 af = *(const bf16x8*)(&Xp[(pt * 16 + l16) * XP_STR + kk * 32 + quad * 8]);
        sacc[pt] = __builtin_amdgcn_mfma_f32_16x16x32_bf16(af, bfm, sacc[pt], 0, 0, 0);
      }
    }
    // ---- bias + rel + mask, in-register softmax over p (column q) ----
    float v[16];
    const float aqv = aqsL[h * 64 + q];
    const float* rel_h = &relLh[h * 169];
    float m = -1e30f;
#pragma unroll
    for (int pt = 0; pt < 4; ++pt)
#pragma unroll
      for (int r = 0; r < 4; ++r) {
        int p = pt * 16 + quad * 4 + r;
        float val = -1e30f;
        if (p < 49) {
          int yp = div7(p), xp = p - yp * 7;
          int fp = regof(gi * 7 + yp) * 3 + regof(gj * 7 + xp);
          val = (sacc[pt][r] + aqv + bpsL[h * 64 + p]) * 0.0625f +
                rel_h[(yp - yq + 6) + 13 * (xp - xq + 6)];
          if (fp != fq) val -= 100.f;
        }
        v[pt * 4 + r] = val;
        m = fmaxf(m, val);
      }
    m = fmaxf(m, __shfl_xor(m, 16));
    m = fmaxf(m, __shfl_xor(m, 32));
    float s = 0.f;
#pragma unroll
    for (int i = 0; i < 16; ++i) { v[i] = __expf(v[i] - m); s += v[i]; }
    s += __shfl_xor(s, 16);
    s += __shfl_xor(s, 32);
    const float inv = 1.f / s;
    __syncthreads();  // B1: prev head-pair's T-phase StB reads complete
    {
      ushort_t* sb = &StB[group][q * 72];
#pragma unroll
      for (int pt = 0; pt < 4; ++pt) {
        ushort4 u;
        u.x = f2b(v[pt * 4 + 0] * inv); u.y = f2b(v[pt * 4 + 1] * inv);
        u.z = f2b(v[pt * 4 + 2] * inv); u.w = f2b(v[pt * 4 + 3] * inv);
        *(ushort4*)(&sb[pt * 16 + quad * 4]) = u;
      }
    }
    __syncthreads();  // B2: wmap^T ready (also fences S global-reads vs T-writes)
    // ---- T: T[d][q] = X . wmap ; store into M_T in-place (cols h*256..) ----
#pragma unroll
    for (int qt = 0; qt < 4; ++qt) {
      f32x4 tacc[4];
#pragma unroll
      for (int dt = 0; dt < 4; ++dt) tacc[dt] = (f32x4){0.f, 0.f, 0.f, 0.f};
#pragma unroll
      for (int kk = 0; kk < 2; ++kk) {
        bf16x8 bfw = *(const bf16x8*)(&StB[group][(qt * 16 + l16) * 72 + kk * 32 + quad * 8]);
#pragma unroll
        for (int dt = 0; dt < 4; ++dt)
          tacc[dt] = __builtin_amdgcn_mfma_f32_16x16x32_bf16(xfr[dt][kk], bfw, tacc[dt], 0, 0, 0);
      }
      int q2 = qt * 16 + l16;
      if (q2 < 49) {
        int t2 = tmap(q2, gi, gj);
#pragma unroll
        for (int dt = 0; dt < 4; ++dt) {
          int d0 = (wv * 4 + dt) * 16 + quad * 4;
          *(ushort4*)(Mn + (size_t)t2 * MSTR + h * 256 + d0) = pack4(tacc[dt]);
        }
      }
    }
  }
}

// ================= gemm3: out[o][t] = Wov3 . T_T^T + cvec =================
__global__ __launch_bounds__(256, 4) void k_gemm3(
    const ushort_t* __restrict__ Wov3, const ushort_t* __restrict__ MT,
    const float* __restrict__ cvec, float* __restrict__ out) {
  __shared__ ushort_t Asm[128 * 72];
  __shared__ ushort_t Bsm[64 * 72];
  const int bx = blockIdx.x;
  const int n = bx / 98, r = bx % 98;
  const int oi = r / 49, tt = r % 49;
  const int o0 = oi * 128, t0 = tt * 64;
  const int tid = threadIdx.x, wave = tid >> 6, lane = tid & 63;
  const int quad = lane >> 4, l16 = lane & 15;
  const ushort_t* Tn = MT + (size_t)n * TROWS * MSTR;
  float* on = out + (size_t)n * 256 * 3136;

  const int arA = tid >> 1, acA = (tid & 1) * 4;  // A: 128 rows x 8 chunks
  const int arB = tid >> 2, acB = (tid & 3) * 2;  // B: 64 rows x 8 chunks
  bf16x8 ra[4], rb[2];
#pragma unroll
  for (int i = 0; i < 4; ++i)
    ra[i] = *(const bf16x8*)(Wov3 + (o0 + arA) * 2048 + (acA + i) * 8);
#pragma unroll
  for (int i = 0; i < 2; ++i)
    rb[i] = *(const bf16x8*)(Tn + (size_t)(t0 + arB) * MSTR + (acB + i) * 8);

  f32x4 acc[2][4];
#pragma unroll
  for (int i = 0; i < 2; ++i)
#pragma unroll
    for (int j = 0; j < 4; ++j) acc[i][j] = (f32x4){0.f, 0.f, 0.f, 0.f};

  for (int kit = 0; kit < 32; ++kit) {
#pragma unroll
    for (int i = 0; i < 4; ++i) *(bf16x8*)(&Asm[arA * 72 + (acA + i) * 8]) = ra[i];
#pragma unroll
    for (int i = 0; i < 2; ++i) *(bf16x8*)(&Bsm[arB * 72 + (acB + i) * 8]) = rb[i];
    __syncthreads();
    if (kit < 31) {
      int k0 = (kit + 1) * 64;
#pragma unroll
      for (int i = 0; i < 4; ++i)
        ra[i] = *(const bf16x8*)(Wov3 + (o0 + arA) * 2048 + k0 + (acA + i) * 8);
#pragma unroll
      for (int i = 0; i < 2; ++i)
        rb[i] = *(const bf16x8*)(Tn + (size_t)(t0 + arB) * MSTR + k0 + (acB + i) * 8);
    }
#pragma unroll
    for (int kk = 0; kk < 2; ++kk) {
      bf16x8 af[2], bf[4];
#pragma unroll
      for (int i = 0; i < 2; ++i)
        af[i] = *(const bf16x8*)(&Asm[((wave * 2 + i) * 16 + l16) * 72 + kk * 32 + quad * 8]);
#pragma unroll
      for (int j = 0; j < 4; ++j)
        bf[j] = *(const bf16x8*)(&Bsm[(j * 16 + l16) * 72 + kk * 32 + quad * 8]);
#pragma unroll
      for (int i = 0; i < 2; ++i)
#pragma unroll
        for (int j = 0; j < 4; ++j)
          acc[i][j] = __builtin_amdgcn_mfma_f32_16x16x32_bf16(af[i], bf[j], acc[i][j], 0, 0, 0);
    }
    __syncthreads();
  }
  // epilogue: + cvec, coalesced fp32 stores
#pragma unroll
  for (int i = 0; i < 2; ++i) {
    const int ob = o0 + (wave * 2 + i) * 16 + quad * 4;
    const float4 cv = *(const float4*)(cvec + ob);
#pragma unroll
    for (int j = 0; j < 4; ++j) {
      const int tg = t0 + j * 16 + l16;
      on[(size_t)(ob + 0) * 3136 + tg] = acc[i][j][0] + cv.x;
      on[(size_t)(ob + 1) * 3136 + tg] = acc[i][j][1] + cv.y;
      on[(size_t)(ob + 2) * 3136 + tg] = acc[i][j][2] + cv.z;
      on[(size_t)(ob + 3) * 3136 + tg] = acc[i][j][3] + cv.w;
    }
  }
}

extern "C" void kernel_launch(void* const* d_in, const int* in_sizes, int n_in,
                              void* d_out, int out_size, void* d_ws, size_t ws_size,
                              hipStream_t stream) {
  (void)in_sizes; (void)n_in; (void)out_size; (void)ws_size;
  const float* X  = (const float*)d_in[0];
  const float* Wk = (const float*)d_in[1];
  const float* bk = (const float*)d_in[2];
  const float* Wq = (const float*)d_in[3];
  const float* bq = (const float*)d_in[4];
  const float* Wv = (const float*)d_in[5];
  const float* bv = (const float*)d_in[6];
  const float* Wo = (const float*)d_in[7];
  const float* bo = (const float*)d_in[8];
  const float* rc = (const float*)d_in[9];

  ushort_t* MT    = (ushort_t*)d_ws;                       // 8*3200*2176 = 55,705,600 u16
  ushort_t* Xroll = MT + (size_t)8 * TROWS * MSTR;         // 8*3200*256  =  6,553,600 u16
  ushort_t* Aext  = Xroll + (size_t)8 * TROWS * 256;       // 2176*256    =    557,056 u16
  ushort_t* Wov3  = Aext + 2176 * 256;                     // 256*2048    =    524,288 u16
  float* fbase = (float*)(Wov3 + 256 * 2048);
  float* cvec  = fbase;         // 256 f32
  float* relL2 = fbase + 256;   // 8*169 f32
  float* out = (float*)d_out;

  k_prep <<<dim3(1290), dim3(256), 0, stream>>>(Wk, Wq, Wo, Wv, bk, bq, bv, bo, rc,
                                                Aext, Wov3, cvec, relL2);
  k_conv <<<dim3(8 * 57), dim3(256), 0, stream>>>(X, Xroll);
  k_gemm1<<<dim3(8 * 425), dim3(256), 0, stream>>>(Xroll, Aext, MT);
  k_attn2<<<dim3(8 * 64), dim3(512), 0, stream>>>(Xroll, MT, relL2);
  k_gemm3<<<dim3(8 * 98), dim3(256), 0, stream>>>(Wov3, MT, cvec, out);
}

// Round 6
// 316.970 us; speedup vs baseline: 10.0107x; 1.0760x over previous
//
#include <hip/hip_runtime.h>
#include <hip/hip_bf16.h>

// Swin window MHSA, MI355X, round 6.
//   k_prep : Aext[2176x256]=G'(+w1/w2 rows), Wov3[256x2048], cvec, relL2(+c0)
//   k_conv : X fp32 -> rolled bf16 Xroll[n][3200][256]  (coalesced stores)
//   k_gemm1: M_T[t][a'] = Xroll . Aext^T  -- BK=256 single-barrier, DMA B-fill
//   k_attn2: per (n,window): S=Xp.M, softmax, T=X.wmap; T overwrites M in-place
//   k_gemm3: out[o][t] = Wov3 . T_T^T + cvec  -- 128x128, BK=128, DMA fills

#define NBATCH 8
#define MSTR   2176           // M_T / T_T row stride (a'-dim, 17 tiles of 128)
#define TROWS  3200           // padded token rows (25 tiles of 128)

typedef unsigned short ushort_t;
typedef __attribute__((ext_vector_type(8))) short bf16x8;   // 8 bf16 = 4 VGPR
typedef __attribute__((ext_vector_type(8))) unsigned short u16x8;
typedef __attribute__((ext_vector_type(4))) float f32x4;    // MFMA acc

__device__ __forceinline__ float b2f(ushort_t u) {
  union { unsigned int i; float f; } v; v.i = ((unsigned int)u) << 16; return v.f;
}
__device__ __forceinline__ ushort_t f2b(float f) {
  union { float f; unsigned int u; } v; v.f = f;
  unsigned int u = v.u;
  return (ushort_t)((u + 0x7FFFu + ((u >> 16) & 1u)) >> 16);
}
__device__ __forceinline__ int regof(int y) { return (y < 49) ? 0 : ((y < 53) ? 1 : 2); }
__device__ __forceinline__ int div7(int t) { return (t * 37) >> 8; }  // t/7, t<64
__device__ __forceinline__ int tmap(int p, int gi, int gj) {
  int wi = div7(p); return (gi * 7 + wi) * 56 + gj * 7 + (p - wi * 7);
}
__device__ __forceinline__ ushort4 pack4(f32x4 a) {
  ushort4 u; u.x = f2b(a[0]); u.y = f2b(a[1]); u.z = f2b(a[2]); u.w = f2b(a[3]);
  return u;
}
// async global->LDS, 16B per lane; lds dest must be wave-uniform base
__device__ __forceinline__ void gload_lds16(const ushort_t* g, ushort_t* l) {
  __builtin_amdgcn_global_load_lds(
      (const __attribute__((address_space(1))) void*)g,
      (__attribute__((address_space(3))) void*)l, 16, 0, 0);
}

// ================= prep (unchanged from R5) =================
__global__ void k_prep(const float* __restrict__ Wk, const float* __restrict__ Wq,
                       const float* __restrict__ Wo, const float* __restrict__ Wv,
                       const float* __restrict__ bk, const float* __restrict__ bq,
                       const float* __restrict__ bv, const float* __restrict__ bo,
                       const float* __restrict__ relc,
                       ushort_t* __restrict__ Aext, ushort_t* __restrict__ Wov3,
                       float* __restrict__ cvec, float* __restrict__ relL2) {
  __shared__ float red[8];
  int blk = blockIdx.x, t = threadIdx.x;
  if (blk < 512) {
    int h = blk >> 6, b0 = (blk & 63) << 2, a = t;
    const float* wkh = Wk + h * 65536;
    const float* wqh = Wq + h * 65536;
    float a0 = 0.f, a1 = 0.f, a2 = 0.f, a3 = 0.f;
    for (int dd = 0; dd < 256; ++dd) {
      float wk = wkh[dd * 256 + a];
      float4 w4 = *(const float4*)(wqh + dd * 256 + b0);
      a0 += wk * w4.x; a1 += wk * w4.y; a2 += wk * w4.z; a3 += wk * w4.w;
    }
    ushort4 u; u.x = f2b(a0); u.y = f2b(a1); u.z = f2b(a2); u.w = f2b(a3);
    *(ushort4*)(Aext + (h * 256 + a) * 256 + b0) = u;
  } else if (blk < 1024) {
    int bb = blk - 512;
    int h = bb >> 6, o0 = (bb & 63) << 2, d = t;
    float a0 = 0.f, a1 = 0.f, a2 = 0.f, a3 = 0.f;
    for (int dd = 0; dd < 256; ++dd) {
      float wv = Wv[(h * 256 + dd) * 256 + d];
      a0 += Wo[(o0 + 0) * 2048 + h * 256 + dd] * wv;
      a1 += Wo[(o0 + 1) * 2048 + h * 256 + dd] * wv;
      a2 += Wo[(o0 + 2) * 2048 + h * 256 + dd] * wv;
      a3 += Wo[(o0 + 3) * 2048 + h * 256 + dd] * wv;
    }
    Wov3[(o0 + 0) * 2048 + h * 256 + d] = f2b(a0);
    Wov3[(o0 + 1) * 2048 + h * 256 + d] = f2b(a1);
    Wov3[(o0 + 2) * 2048 + h * 256 + d] = f2b(a2);
    Wov3[(o0 + 3) * 2048 + h * 256 + d] = f2b(a3);
  } else if (blk < 1032) {
    int h = blk - 1024;
    float s1 = 0.f, s2 = 0.f;
    for (int dd = 0; dd < 256; ++dd) {
      s1 += bk[h * 256 + dd] * Wq[(h * 256 + dd) * 256 + t];
      s2 += bq[h * 256 + dd] * Wk[(h * 256 + dd) * 256 + t];
    }
    Aext[(2048 + h) * 256 + t] = f2b(s1);
    Aext[(2056 + h) * 256 + t] = f2b(s2);
  } else if (blk == 1032) {
    for (int i = t; i < 112 * 256 / 8; i += 256)
      *(u16x8*)(Aext + 2064 * 256 + i * 8) = (u16x8){0,0,0,0,0,0,0,0};
  } else if (blk < 1289) {
    int o = blk - 1033;
    const float* wob = Wo + o * 2048;
    float acc = 0.f;
#pragma unroll
    for (int j = 0; j < 8; ++j) acc += wob[j * 256 + t] * bv[j * 256 + t];
#pragma unroll
    for (int s = 1; s < 64; s <<= 1) acc += __shfl_xor(acc, s);
    if ((t & 63) == 0) red[t >> 6] = acc;
    __syncthreads();
    if (t == 0) cvec[o] = bo[o] + red[0] + red[1] + red[2] + red[3];
  } else {
    if (t < 8) {
      float c = 0.f;
      for (int dd = 0; dd < 256; ++dd) c += bk[t * 256 + dd] * bq[t * 256 + dd];
      red[t] = c * 0.0625f;
    }
    __syncthreads();
    for (int i = t; i < 8 * 169; i += 256) {
      int h = i / 169, idx = i - h * 169;
      relL2[i] = relc[idx * 8 + h] + red[h];
    }
  }
}

// ================= conv: rolled gather, coalesced bf16 stores =============
__global__ void k_conv(const float* __restrict__ X, ushort_t* __restrict__ Xroll) {
  const int n = blockIdx.x / 57, y = blockIdx.x % 57;
  ushort_t* xr = Xroll + (size_t)n * TROWS * 256;
  const int d = threadIdx.x;
  if (y == 56) {  // zero pad rows 3136..3199
    for (int i = d; i < 64 * 256 / 8; i += 256)
      *(u16x8*)(xr + 3136 * 256 + i * 8) = (u16x8){0,0,0,0,0,0,0,0};
    return;
  }
  const int c = d >> 4, p1 = (d >> 2) & 3, p2 = d & 3;
  const int sp = c * 16 + (((p1 + 1) & 3) << 2) + ((p2 + 1) & 3);
  const int ty = (p1 == 3) ? y : ((y == 0) ? 55 : y - 1);
  const float* rowp = X + (size_t)n * 256 * 3136 + sp * 3136 + ty * 56;
  ushort_t* orow = xr + y * 56 * 256 + d;
  for (int x = 0; x < 56; ++x) {
    int tx = (p2 == 3) ? x : ((x == 0) ? 55 : x - 1);
    orow[x * 256] = f2b(rowp[tx]);   // 256 lanes -> 512B contiguous store
  }
}

// ================= gemm1: M_T[t][a'] = Xroll . Aext^T =====================
// BK=256 (full K): one DMA fill of B[128][256] (swizzled), ONE barrier,
// then pure MFMA with A-frags streamed from L2-resident Aext.
__global__ __launch_bounds__(256, 2) void k_gemm1(
    const ushort_t* __restrict__ Xroll, const ushort_t* __restrict__ Aext,
    ushort_t* __restrict__ MT) {
  __shared__ ushort_t Bsm[128 * 256];   // 64 KB
  const int bx = blockIdx.x;
  const int n = bx / 425, r = bx % 425;
  const int tt = r / 17, aa = r % 17;
  const int a0 = aa * 128, t0 = tt * 128;
  const int tid = threadIdx.x, wave = tid >> 6, lane = tid & 63;
  const int quad = lane >> 4, l16 = lane & 15;
  const int wa = wave >> 1, wt = wave & 1;
  const ushort_t* Xn = Xroll + (size_t)n * TROWS * 256;
  ushort_t* Mn = MT + (size_t)n * TROWS * MSTR;

  // fill: slot S holds 16B chunk (r=S>>5, c=(S&24)|((S^r)&7)) of row t0+r
#pragma unroll
  for (int i = 0; i < 16; ++i) {
    int S = i * 256 + tid;
    int rr = S >> 5, sc = S & 31;
    int c = (sc & 24) | ((sc ^ rr) & 7);
    gload_lds16(Xn + (t0 + rr) * 256 + c * 8, &Bsm[(i * 256 + wave * 64) * 8]);
  }
  __syncthreads();  // the only barrier

  f32x4 acc[4][4];
#pragma unroll
  for (int i = 0; i < 4; ++i)
#pragma unroll
    for (int j = 0; j < 4; ++j) acc[i][j] = (f32x4){0.f, 0.f, 0.f, 0.f};

  const ushort_t* abase = Aext + (a0 + wa * 64 + l16) * 256 + quad * 8;
  const int sw = l16 & 7;
  bf16x8 af[4], afn[4];
#pragma unroll
  for (int i = 0; i < 4; ++i) af[i] = *(const bf16x8*)(abase + i * 4096);
#pragma unroll
  for (int kk = 0; kk < 8; ++kk) {
    if (kk < 7) {
#pragma unroll
      for (int i = 0; i < 4; ++i)
        afn[i] = *(const bf16x8*)(abase + i * 4096 + (kk + 1) * 32);
    }
    bf16x8 bf[4];
#pragma unroll
    for (int j = 0; j < 4; ++j) {
      int rr = wt * 64 + j * 16 + l16;
      int c = kk * 4 + quad;
      int pos = (c & 24) | ((c ^ sw) & 7);
      bf[j] = *(const bf16x8*)(&Bsm[rr * 256 + pos * 8]);
    }
#pragma unroll
    for (int i = 0; i < 4; ++i)
#pragma unroll
      for (int j = 0; j < 4; ++j)
        acc[i][j] = __builtin_amdgcn_mfma_f32_16x16x32_bf16(af[i], bf[j], acc[i][j], 0, 0, 0);
    if (kk < 7) {
#pragma unroll
      for (int i = 0; i < 4; ++i) af[i] = afn[i];
    }
  }
  // store C transposed: M_T[t][a']
#pragma unroll
  for (int i = 0; i < 4; ++i)
#pragma unroll
    for (int j = 0; j < 4; ++j) {
      int tg = t0 + wt * 64 + j * 16 + l16;
      int ag = a0 + wa * 64 + i * 16 + quad * 4;
      *(ushort4*)(Mn + (size_t)tg * MSTR + ag) = pack4(acc[i][j]);
    }
}

// ================= attn2 (unchanged from R5) ==============================
#define XP_STR 264
__global__ __launch_bounds__(512, 4) void k_attn2(
    const ushort_t* __restrict__ Xroll, ushort_t* __restrict__ MT,
    const float* __restrict__ relL2) {
  __shared__ ushort_t Xp[64 * XP_STR];
  __shared__ ushort_t StB[2][64 * 72];
  __shared__ float aqsL[8 * 64];
  __shared__ float bpsL[8 * 64];
  __shared__ float relLh[8 * 169];

  const int tid = threadIdx.x;
  const int wave = tid >> 6, lane = tid & 63;
  const int quad = lane >> 4, l16 = lane & 15;
  const int group = wave >> 2, wv = wave & 3;
  const int n = blockIdx.x >> 6, g = blockIdx.x & 63;
  const int gi = g >> 3, gj = g & 7;
  const ushort_t* Xn = Xroll + (size_t)n * TROWS * 256;
  ushort_t* Mn = MT + (size_t)n * TROWS * MSTR;

  {
    const int p = tid & 63, cg = tid >> 6;
    if (p < 49) {
      int t = tmap(p, gi, gj);
#pragma unroll
      for (int i = 0; i < 4; ++i)
        *(u16x8*)(&Xp[p * XP_STR + (cg * 4 + i) * 8]) =
            *(const u16x8*)(Xn + t * 256 + (cg * 4 + i) * 8);
    } else {
#pragma unroll
      for (int i = 0; i < 4; ++i)
        *(u16x8*)(&Xp[p * XP_STR + (cg * 4 + i) * 8]) = (u16x8){0,0,0,0,0,0,0,0};
    }
  }
  for (int i = tid; i < 8 * 169; i += 512) relLh[i] = relL2[i];
  {
    const int h = tid >> 6, q = tid & 63;
    int qq = (q < 49) ? q : 48;
    int t = tmap(qq, gi, gj);
    aqsL[h * 64 + q] = b2f(Mn[(size_t)t * MSTR + 2048 + h]);
    bpsL[h * 64 + q] = b2f(Mn[(size_t)t * MSTR + 2056 + h]);
  }
  __syncthreads();

  bf16x8 xfr[4][2];
#pragma unroll
  for (int dt = 0; dt < 4; ++dt) {
    const int d = (wv * 4 + dt) * 16 + l16;
#pragma unroll
    for (int kk = 0; kk < 2; ++kk)
#pragma unroll
      for (int j = 0; j < 8; ++j)
        xfr[dt][kk][j] = (short)Xp[(kk * 32 + quad * 8 + j) * XP_STR + d];
  }

  const int q = wv * 16 + l16;
  const int qq = (q < 49) ? q : 48;
  const int tq = tmap(qq, gi, gj);
  const ushort_t* Mbase = Mn + (size_t)tq * MSTR + quad * 8;
  const int yq = div7(qq), xq = qq - yq * 7;
  const int fq = regof(gi * 7 + yq) * 3 + regof(gj * 7 + xq);

  for (int hh = 0; hh < 4; ++hh) {
    const int h = hh * 2 + group;
    f32x4 sacc[4];
#pragma unroll
    for (int pt = 0; pt < 4; ++pt) sacc[pt] = (f32x4){0.f, 0.f, 0.f, 0.f};
    const ushort_t* mrow = Mbase + h * 256;
#pragma unroll
    for (int kk = 0; kk < 8; ++kk) {
      bf16x8 bfm = *(const bf16x8*)(mrow + kk * 32);
#pragma unroll
      for (int pt = 0; pt < 4; ++pt) {
        bf16x8 af = *(const bf16x8*)(&Xp[(pt * 16 + l16) * XP_STR + kk * 32 + quad * 8]);
        sacc[pt] = __builtin_amdgcn_mfma_f32_16x16x32_bf16(af, bfm, sacc[pt], 0, 0, 0);
      }
    }
    float v[16];
    const float aqv = aqsL[h * 64 + q];
    const float* rel_h = &relLh[h * 169];
    float m = -1e30f;
#pragma unroll
    for (int pt = 0; pt < 4; ++pt)
#pragma unroll
      for (int r = 0; r < 4; ++r) {
        int p = pt * 16 + quad * 4 + r;
        float val = -1e30f;
        if (p < 49) {
          int yp = div7(p), xp = p - yp * 7;
          int fp = regof(gi * 7 + yp) * 3 + regof(gj * 7 + xp);
          val = (sacc[pt][r] + aqv + bpsL[h * 64 + p]) * 0.0625f +
                rel_h[(yp - yq + 6) + 13 * (xp - xq + 6)];
          if (fp != fq) val -= 100.f;
        }
        v[pt * 4 + r] = val;
        m = fmaxf(m, val);
      }
    m = fmaxf(m, __shfl_xor(m, 16));
    m = fmaxf(m, __shfl_xor(m, 32));
    float s = 0.f;
#pragma unroll
    for (int i = 0; i < 16; ++i) { v[i] = __expf(v[i] - m); s += v[i]; }
    s += __shfl_xor(s, 16);
    s += __shfl_xor(s, 32);
    const float inv = 1.f / s;
    __syncthreads();
    {
      ushort_t* sb = &StB[group][q * 72];
#pragma unroll
      for (int pt = 0; pt < 4; ++pt) {
        ushort4 u;
        u.x = f2b(v[pt * 4 + 0] * inv); u.y = f2b(v[pt * 4 + 1] * inv);
        u.z = f2b(v[pt * 4 + 2] * inv); u.w = f2b(v[pt * 4 + 3] * inv);
        *(ushort4*)(&sb[pt * 16 + quad * 4]) = u;
      }
    }
    __syncthreads();
#pragma unroll
    for (int qt = 0; qt < 4; ++qt) {
      f32x4 tacc[4];
#pragma unroll
      for (int dt = 0; dt < 4; ++dt) tacc[dt] = (f32x4){0.f, 0.f, 0.f, 0.f};
#pragma unroll
      for (int kk = 0; kk < 2; ++kk) {
        bf16x8 bfw = *(const bf16x8*)(&StB[group][(qt * 16 + l16) * 72 + kk * 32 + quad * 8]);
#pragma unroll
        for (int dt = 0; dt < 4; ++dt)
          tacc[dt] = __builtin_amdgcn_mfma_f32_16x16x32_bf16(xfr[dt][kk], bfw, tacc[dt], 0, 0, 0);
      }
      int q2 = qt * 16 + l16;
      if (q2 < 49) {
        int t2 = tmap(q2, gi, gj);
#pragma unroll
        for (int dt = 0; dt < 4; ++dt) {
          int d0 = (wv * 4 + dt) * 16 + quad * 4;
          *(ushort4*)(Mn + (size_t)t2 * MSTR + h * 256 + d0) = pack4(tacc[dt]);
        }
      }
    }
  }
}

// ================= gemm3: out[o][t] = Wov3 . T_T^T + cvec =================
// 128o x 128t tile, BK=128, 16 k-iters, DMA fills with XOR swizzle.
__global__ __launch_bounds__(256, 2) void k_gemm3(
    const ushort_t* __restrict__ Wov3, const ushort_t* __restrict__ MT,
    const float* __restrict__ cvec, float* __restrict__ out) {
  __shared__ ushort_t Asm[128 * 128];   // 32 KB
  __shared__ ushort_t Bsm[128 * 128];   // 32 KB
  const int bx = blockIdx.x;
  const int n = bx / 50, r2 = bx % 50;
  const int oi = r2 / 25, tt = r2 % 25;
  const int o0 = oi * 128, t0 = tt * 128;
  const int tid = threadIdx.x, wave = tid >> 6, lane = tid & 63;
  const int quad = lane >> 4, l16 = lane & 15;
  const int wa = wave >> 1, wt = wave & 1;
  const ushort_t* Tn = MT + (size_t)n * TROWS * MSTR;
  float* on = out + (size_t)n * 256 * 3136;
  const int sw = l16 & 7;

  f32x4 acc[4][4];
#pragma unroll
  for (int i = 0; i < 4; ++i)
#pragma unroll
    for (int j = 0; j < 4; ++j) acc[i][j] = (f32x4){0.f, 0.f, 0.f, 0.f};

  for (int kit = 0; kit < 16; ++kit) {
    const int kb = kit * 128;
    // fill A[128][128] and B[128][128], 16B chunks, swizzle c^=(r&7)
#pragma unroll
    for (int i = 0; i < 8; ++i) {
      int S = i * 256 + tid;
      int rr = S >> 4, sc = S & 15;
      int c = (sc & 8) | ((sc ^ rr) & 7);
      gload_lds16(Wov3 + (o0 + rr) * 2048 + kb + c * 8,
                  &Asm[(i * 256 + wave * 64) * 8]);
    }
#pragma unroll
    for (int i = 0; i < 8; ++i) {
      int S = i * 256 + tid;
      int rr = S >> 4, sc = S & 15;
      int c = (sc & 8) | ((sc ^ rr) & 7);
      gload_lds16(Tn + (size_t)(t0 + rr) * MSTR + kb + c * 8,
                  &Bsm[(i * 256 + wave * 64) * 8]);
    }
    __syncthreads();
#pragma unroll
    for (int kk = 0; kk < 4; ++kk) {
      bf16x8 af[4], bf[4];
      const int c = kk * 4 + quad;
      const int pos = (c & 8) | ((c ^ sw) & 7);
#pragma unroll
      for (int i = 0; i < 4; ++i)
        af[i] = *(const bf16x8*)(&Asm[(wa * 64 + i * 16 + l16) * 128 + pos * 8]);
#pragma unroll
      for (int j = 0; j < 4; ++j)
        bf[j] = *(const bf16x8*)(&Bsm[(wt * 64 + j * 16 + l16) * 128 + pos * 8]);
#pragma unroll
      for (int i = 0; i < 4; ++i)
#pragma unroll
        for (int j = 0; j < 4; ++j)
          acc[i][j] = __builtin_amdgcn_mfma_f32_16x16x32_bf16(af[i], bf[j], acc[i][j], 0, 0, 0);
    }
    __syncthreads();
  }
  // epilogue: + cvec, guard pad tokens
#pragma unroll
  for (int i = 0; i < 4; ++i) {
    const int ob = o0 + wa * 64 + i * 16 + quad * 4;
    const float4 cv = *(const float4*)(cvec + ob);
#pragma unroll
    for (int j = 0; j < 4; ++j) {
      const int tg = t0 + wt * 64 + j * 16 + l16;
      if (tg < 3136) {
        on[(size_t)(ob + 0) * 3136 + tg] = acc[i][j][0] + cv.x;
        on[(size_t)(ob + 1) * 3136 + tg] = acc[i][j][1] + cv.y;
        on[(size_t)(ob + 2) * 3136 + tg] = acc[i][j][2] + cv.z;
        on[(size_t)(ob + 3) * 3136 + tg] = acc[i][j][3] + cv.w;
      }
    }
  }
}

extern "C" void kernel_launch(void* const* d_in, const int* in_sizes, int n_in,
                              void* d_out, int out_size, void* d_ws, size_t ws_size,
                              hipStream_t stream) {
  (void)in_sizes; (void)n_in; (void)out_size; (void)ws_size;
  const float* X  = (const float*)d_in[0];
  const float* Wk = (const float*)d_in[1];
  const float* bk = (const float*)d_in[2];
  const float* Wq = (const float*)d_in[3];
  const float* bq = (const float*)d_in[4];
  const float* Wv = (const float*)d_in[5];
  const float* bv = (const float*)d_in[6];
  const float* Wo = (const float*)d_in[7];
  const float* bo = (const float*)d_in[8];
  const float* rc = (const float*)d_in[9];

  ushort_t* MT    = (ushort_t*)d_ws;                       // 8*3200*2176 u16
  ushort_t* Xroll = MT + (size_t)8 * TROWS * MSTR;         // 8*3200*256 u16
  ushort_t* Aext  = Xroll + (size_t)8 * TROWS * 256;       // 2176*256 u16
  ushort_t* Wov3  = Aext + 2176 * 256;                     // 256*2048 u16
  float* fbase = (float*)(Wov3 + 256 * 2048);
  float* cvec  = fbase;         // 256 f32
  float* relL2 = fbase + 256;   // 8*169 f32
  float* out = (float*)d_out;

  k_prep <<<dim3(1290), dim3(256), 0, stream>>>(Wk, Wq, Wo, Wv, bk, bq, bv, bo, rc,
                                                Aext, Wov3, cvec, relL2);
  k_conv <<<dim3(8 * 57), dim3(256), 0, stream>>>(X, Xroll);
  k_gemm1<<<dim3(8 * 425), dim3(256), 0, stream>>>(Xroll, Aext, MT);
  k_attn2<<<dim3(8 * 64), dim3(512), 0, stream>>>(Xroll, MT, relL2);
  k_gemm3<<<dim3(8 * 50), dim3(256), 0, stream>>>(Wov3, MT, cvec, out);
}